// Round 8
// baseline (703.048 us; speedup 1.0000x reference)
//
#include <hip/hip_runtime.h>
#include <hip/hip_bf16.h>
#include <stdint.h>

// ---------------------------------------------------------------------------
// B=16, N=1024, D=256, M=128, C=8192. fp32 in/out, bf16 MFMA internally.
// Output: 3 x [B,N,D] fp32 concatenated.
// Attention fully fused (flash-style). NOTE: all register-array indices in the
// flash kernel MUST be compile-time (runtime index -> scratch spill, R10: 2.3GB
// of spill writes, 7x regression).
// R1: flash 64-wide chunks, 8 phases/kt, partner split on grid.
// R2: 2-phase-deep register prefetch + s_setprio around MFMA clusters.
// R3: XCD-aware 1-D grid swizzle (FETCH 418->74MB).
// R4: __launch_bounds__(256,2) -> 2 waves/SIMD; T13 defer-max.
// R5: PV -> mfma_32x32x16 via wave-pair shared P; shuffle-free softmax.
// R6 (REVERTED): direct-global K gather (512B stride = 16 lines/instr, 2.3x).
// R7: FA_S->64 + XOR chunk swizzle; conflicts 12.6M->6.3M. Flash now ~91%
//     LDS-pipe-busy (576 b128 ops/block-kt) - near its structural floor.
// R8: (a) Pg stride 136->132: 68 dwords==4 mod 32 made pa reads 4-way
//     conflicted (the residual 6.3M); 66 dwords==2 mod 32 -> 2-way = free.
//     (b) hg_prep fuses zero/count/scan/scan/fill (5 serial latency-bound
//     launches -> 1, counters+scan+fill all in LDS).
//     (c) V-GEMM epi=5 stores C^T (bf16) directly: MFMA C-layout is
//     col=lane-fixed, rows-consecutive -> natural ushort4 transposed stores;
//     deletes the transpose_bf16 launch + 24MB traffic.
// ---------------------------------------------------------------------------

namespace {
constexpr int B_ = 16;
constexpr int N_ = 1024;
constexpr int D_ = 256;
constexpr int M_ = 128;
constexpr int C_ = 8192;
constexpr int BN_ = B_ * N_;                       // 16384
constexpr long long BND_ = (long long)BN_ * D_;    // 4,194,304 elems
constexpr int NB_ = N_ * B_;                       // 16384
constexpr int LDA_S = 40;                          // K-loop LDS stride (shorts)
constexpr int EPI_S = 68;                          // epilogue LDS stride (floats)
constexpr int PG_S = 132;                          // flash P stride (shorts): 66 dw == 2 mod 32
}

typedef short bf16x8_t __attribute__((ext_vector_type(8)));
typedef float f32x4_t __attribute__((ext_vector_type(4)));
typedef float f32x16_t __attribute__((ext_vector_type(16)));
typedef unsigned short u16x8_t __attribute__((ext_vector_type(8)));

#define DEV static __device__ __forceinline__
DEV float bf2f(unsigned short u) { return __uint_as_float((unsigned)u << 16); }
DEV unsigned short f2bf_bits(float x) { return __builtin_bit_cast(unsigned short, __float2bfloat16(x)); }

// ---------------------------------------------------------------------------
// NT bf16 MFMA GEMM, 128x128 tile, BK=32, 4 waves, LDS-transposed epilogue.
// epi: 0 = fp32 C = v (v = acc*scale)
//      1 = bf16 C = v + bias[col]
//      2 = fp32 C = relu(v + bias[col] + add0[idx] + add1[idx])
//      4 = bf16 C = v + bias[col]*scale      (i.e. (acc+bias)*scale)
//      5 = bf16 C^T = acc + bias[col], stored to Cv as [mb][col][row%1024]
//          (direct transposed store; Cv = [3*16][256][1024])
// ---------------------------------------------------------------------------
__global__ __launch_bounds__(256) void gemm_nt_kernel(
    const __hip_bfloat16* __restrict__ A0, const __hip_bfloat16* __restrict__ A1,
    int lda, long long sA,
    const __hip_bfloat16* __restrict__ B0, const __hip_bfloat16* __restrict__ B1,
    int ldb, long long sB,
    void* __restrict__ Cv, int ldc, long long sC, long long cOff, long long pieceCs,
    int K, int kPiece, int zBatches,
    float scale, const float* __restrict__ bias,
    const float* __restrict__ add0, const float* __restrict__ add1,
    int epi)
{
    __shared__ __align__(16) char smem[20480];
    short* smA = (short*)smem;
    short* smB = (short*)(smem + 10240);

    const int tid = threadIdx.x;
    const int wid = tid >> 6;
    const int lane = tid & 63;
    const int z = blockIdx.z;
    const int batch = z % zBatches;
    const int rem = z / zBatches;
    const int pi = rem & 1;
    const int kh = rem >> 1;

    const short* Ab = (const short*)(pi ? A1 : A0) + (size_t)batch * sA
                    + (size_t)blockIdx.x * 128 * lda + (size_t)kh * kPiece;
    const short* Bb = (const short*)(pi ? B1 : B0) + (size_t)batch * sB
                    + (size_t)blockIdx.y * 128 * ldb + (size_t)kh * kPiece;

    const int wm = (wid >> 1) * 64;
    const int wn = (wid & 1) * 64;
    const int fr = lane & 15;
    const int kq = (lane >> 4) * 8;
    const int sr = tid >> 2;
    const int sc = (tid & 3) * 8;

    f32x4_t acc[4][4] = {};
    int4 avv[2], bvv[2];
#pragma unroll
    for (int h = 0; h < 2; h++) {
        const int row = h * 64 + sr;
        avv[h] = *(const int4*)(Ab + (size_t)row * lda + sc);
        bvv[h] = *(const int4*)(Bb + (size_t)row * ldb + sc);
    }

    for (int k0 = 0; k0 < K; k0 += 32) {
        __syncthreads();
#pragma unroll
        for (int h = 0; h < 2; h++) {
            const int row = h * 64 + sr;
            *(int4*)&smA[row * LDA_S + sc] = avv[h];
            *(int4*)&smB[row * LDA_S + sc] = bvv[h];
        }
        __syncthreads();

        const int kn = k0 + 32;
        if (kn < K) {
#pragma unroll
            for (int h = 0; h < 2; h++) {
                const int row = h * 64 + sr;
                avv[h] = *(const int4*)(Ab + (size_t)row * lda + (kn + sc));
                bvv[h] = *(const int4*)(Bb + (size_t)row * ldb + (kn + sc));
            }
        }

        bf16x8_t af[4], bfv[4];
#pragma unroll
        for (int i = 0; i < 4; i++)
            af[i] = *(const bf16x8_t*)&smA[(wm + i * 16 + fr) * LDA_S + kq];
#pragma unroll
        for (int j = 0; j < 4; j++)
            bfv[j] = *(const bf16x8_t*)&smB[(wn + j * 16 + fr) * LDA_S + kq];
#pragma unroll
        for (int i = 0; i < 4; i++)
#pragma unroll
            for (int j = 0; j < 4; j++)
                acc[i][j] = __builtin_amdgcn_mfma_f32_16x16x32_bf16(af[i], bfv[j], acc[i][j], 0, 0, 0);
    }

    const int r_ = lane >> 4;

    if (epi == 5) {
        // direct transposed bf16 store: C^T[mb][col d][row n] = acc + bias[col].
        // C layout: lane holds col = fr (fixed), rows r_*4 + [0,4) consecutive
        // -> one ushort4 per (i,j) at Vt + mb*D_*1024 + col*1024 + nl.
#pragma unroll
        for (int i = 0; i < 4; i++) {
            const int row = blockIdx.x * 128 + wm + i * 16 + r_ * 4;
            const int mb = row >> 10;
            const int nl = row & 1023;
#pragma unroll
            for (int j = 0; j < 4; j++) {
                const int col = blockIdx.y * 128 + wn + j * 16 + fr;
                const float bb = bias[col];
                ushort4 pk;
                pk.x = f2bf_bits(acc[i][j][0] + bb);
                pk.y = f2bf_bits(acc[i][j][1] + bb);
                pk.z = f2bf_bits(acc[i][j][2] + bb);
                pk.w = f2bf_bits(acc[i][j][3] + bb);
                *(ushort4*)((unsigned short*)Cv + ((size_t)mb * D_ + col) * 1024 + nl) = pk;
            }
        }
        return;
    }

    float* lts = (float*)smem + wid * (16 * EPI_S);
#pragma unroll
    for (int i = 0; i < 4; i++) {
        __syncthreads();
#pragma unroll
        for (int j = 0; j < 4; j++)
#pragma unroll
            for (int r = 0; r < 4; r++)
                lts[(r_ * 4 + r) * EPI_S + j * 16 + fr] = acc[i][j][r] * scale;
        __syncthreads();
#pragma unroll
        for (int t = 0; t < 4; t++) {
            const int lrow = t * 4 + r_;
            const f32x4_t v4 = *(const f32x4_t*)&lts[lrow * EPI_S + fr * 4];
            const int row = blockIdx.x * 128 + wm + i * 16 + lrow;
            const int col = blockIdx.y * 128 + wn + fr * 4;
            const size_t idx = (size_t)batch * sC + (size_t)row * ldc + col;
            const size_t gidx = (size_t)cOff + (size_t)rem * pieceCs + idx;
            if (epi == 0) {
                *(f32x4_t*)((float*)Cv + gidx) = v4;
            } else if (epi == 1 || epi == 4) {
                f32x4_t bb = {0.f, 0.f, 0.f, 0.f};
                if (bias) bb = *(const f32x4_t*)(bias + col);
                const float bs = (epi == 4) ? scale : 1.0f;
                ushort4 pk;
                pk.x = f2bf_bits(v4[0] + bb[0] * bs);
                pk.y = f2bf_bits(v4[1] + bb[1] * bs);
                pk.z = f2bf_bits(v4[2] + bb[2] * bs);
                pk.w = f2bf_bits(v4[3] + bb[3] * bs);
                *(ushort4*)((unsigned short*)Cv + gidx) = pk;
            } else {
                const f32x4_t bb = *(const f32x4_t*)(bias + col);
                const f32x4_t m0 = *(const f32x4_t*)(add0 + idx);
                const f32x4_t m1 = *(const f32x4_t*)(add1 + idx);
                f32x4_t o;
#pragma unroll
                for (int k = 0; k < 4; k++) {
                    float v = v4[k] + bb[k] + m0[k] + m1[k];
                    o[k] = v > 0.0f ? v : 0.0f;
                }
                *(f32x4_t*)((float*)Cv + gidx) = o;
            }
        }
    }
}

// ---------------------------------------------------------------------------
// Fused flash attention. 1-D grid of 1536 slots, XCD-swizzled (R3).
// Block = 64 Q-rows of one (m,batch,partner). Per kv-tile kt: 8 phases of
// 128x64 bf16 chunks (4 K d-chunks, then 4 V chunks) into 2x16KB ping-pong;
// ONE barrier per phase, 2-deep register prefetch.
// LDS layout: linear [128][64] shorts with XOR chunk swizzle c' = c ^ (row&7)
// on write and both reads. Pg stride = PG_S=132 (66 dw == 2 mod 32: pa reads
// 2-way = free, P writes conflict-free).
// QK^T: 16x16x32, wave w owns q-rows w*16+[0,16).
// PV:   32x32x16, wave-pair shares P; wave (qg,dh) owns 32q x {dh*64 cols}.
// Softmax: per-lane partial max + __all trigger; lrun per-lane, reduced at
// epilogue; defer-max rescale at vp==0 via LDS alpha array.
// Msg[p][m][b][n][d] fp32 = softmax(Q_m K_p^T /16) @ V_p
// ---------------------------------------------------------------------------
__global__ __launch_bounds__(256, 2) void flash_attn_kernel(
    const __hip_bfloat16* __restrict__ Qall,   // [3][16][1024][256] bf16, pre-scaled by 1/16
    const __hip_bfloat16* __restrict__ Kall,   // [3][16][1024][256] bf16
    const __hip_bfloat16* __restrict__ Vt,     // [3][16][256][1024] bf16
    float* __restrict__ Msg)                   // [2][3][16][1024][256] fp32
{
    __shared__ __align__(16) short smKV[2][128 * 64];    // 2 x 16384 B ping-pong
    __shared__ __align__(16) short smP2[2][32 * PG_S];   // wave-pair shared P
    __shared__ float lrS[64];
    __shared__ float alS[64];
    __shared__ int   flS[4];

    const int tid = threadIdx.x;
    const int w = tid >> 6;
    const int lane = tid & 63;
    const int fr = lane & 15;
    const int qd = lane >> 4;
    const int l31 = lane & 31;
    const int hi = lane >> 5;
    const int qg = w >> 1;           // PV q-group (rows qg*32 + [0,32))
    const int dh = w & 1;            // PV d-subcolumn selector

    // XCD-aware decode: slot -> (qt, batch, zz). Bijective on [0,1536).
    const int slot = blockIdx.x;
    const int xcd = slot & 7;
    const int t_ = slot >> 3;
    const int qt = t_ & 15;
    const int gh = t_ >> 4;          // g/8, 0..11
    const int g = gh * 8 + xcd;      // group = batch + 16*zz, 0..95
    const int batch = g & 15;
    const int zz = g >> 4;           // 0..5
    const int m = zz >> 1;
    const int p = zz & 1;
    const int pn = (p == 0) ? (m == 0 ? 1 : 0) : (m == 2 ? 1 : 2);

    short* Pg = smP2[qg];            // [32][PG_S]

    // Q fragments: A[m=fr][k=qd*8+j] for 8 d-chunks, wave rows qt*64+w*16+fr
    const size_t qrow = ((size_t)(m * 16 + batch) * 1024) + qt * 64 + w * 16 + fr;
    const short* qp = (const short*)Qall + qrow * 256 + qd * 8;
    bf16x8_t qa[8];
#pragma unroll
    for (int c = 0; c < 8; c++) qa[c] = *(const bf16x8_t*)(qp + c * 32);

    const short* Kb = (const short*)Kall + ((size_t)(pn * 16 + batch) * 1024) * 256;
    const short* Vb = (const short*)Vt + ((size_t)(pn * 16 + batch) * 256) * 1024;

    const int row0 = tid >> 2;            // staging row 0..63 (plus +64)
    const int row1 = row0 + 64;
    const int colb = (tid & 3) * 16;      // global staging short-col (2 int4/row)
    // swizzled LDS chunk offsets (shorts) for this lane's two 16B chunks
    const int swkey = (tid >> 2) & 7;
    const int cA8 = (((tid & 3) * 2) ^ swkey) * 8;
    const int cB8 = (((tid & 3) * 2 + 1) ^ swkey) * 8;

    f32x16_t Op4[4] = {};                 // O[32q x 32d] tiles: i = h*2+dt
    float mrun[4] = {-1e30f, -1e30f, -1e30f, -1e30f};
    float lrun[4] = {0.f, 0.f, 0.f, 0.f}; // PER-LANE partial sums

#define LOADSET(p0, p1, p2, p3, base, stride)                                  \
    do {                                                                       \
        const short* _b = (base);                                              \
        p0 = *(const int4*)(_b + (size_t)row0 * (stride));                     \
        p1 = *(const int4*)(_b + (size_t)row0 * (stride) + 8);                 \
        p2 = *(const int4*)(_b + (size_t)row1 * (stride));                     \
        p3 = *(const int4*)(_b + (size_t)row1 * (stride) + 8);                 \
    } while (0)

    // prologue: phase 0 (K dc=0) into stE, phase 1 (K dc=1) into stO
    int4 e0, e1, e2, e3, o0, o1, o2, o3;
    LOADSET(e0, e1, e2, e3, Kb + colb, 256);
    LOADSET(o0, o1, o2, o3, Kb + 64 + colb, 256);

    for (int kt = 0; kt < 8; kt++) {
        f32x4_t S[8] = {};
#pragma unroll
        for (int pp = 0; pp < 8; pp++) {               // COMPILE-TIME phases
            short* buf = smKV[pp & 1];                 // kt*8 even -> pp&1
            if ((pp & 1) == 0) {
                *(int4*)&buf[row0 * 64 + cA8] = e0;
                *(int4*)&buf[row0 * 64 + cB8] = e1;
                *(int4*)&buf[row1 * 64 + cA8] = e2;
                *(int4*)&buf[row1 * 64 + cB8] = e3;
            } else {
                *(int4*)&buf[row0 * 64 + cA8] = o0;
                *(int4*)&buf[row0 * 64 + cB8] = o1;
                *(int4*)&buf[row1 * 64 + cA8] = o2;
                *(int4*)&buf[row1 * 64 + cB8] = o3;
            }
            __syncthreads();
            // issue loads for phase pp+2 (into the set just drained to LDS).
            // phase->data map: ph 0..3 = K d-chunk ph of kt; ph 4..7 = V chunk
            // q=ph-4 (h=q>>1 d-half, kh=q&1 kv-half) of kt.
            if (pp == 0) {
                LOADSET(e0, e1, e2, e3, Kb + (size_t)(kt * 128) * 256 + 128 + colb, 256);
            } else if (pp == 1) {
                LOADSET(o0, o1, o2, o3, Kb + (size_t)(kt * 128) * 256 + 192 + colb, 256);
            } else if (pp == 2) {
                LOADSET(e0, e1, e2, e3, Vb + (size_t)kt * 128 + colb, 1024);
            } else if (pp == 3) {
                LOADSET(o0, o1, o2, o3, Vb + (size_t)kt * 128 + 64 + colb, 1024);
            } else if (pp == 4) {
                LOADSET(e0, e1, e2, e3, Vb + (size_t)128 * 1024 + kt * 128 + colb, 1024);
            } else if (pp == 5) {
                LOADSET(o0, o1, o2, o3, Vb + (size_t)128 * 1024 + kt * 128 + 64 + colb, 1024);
            } else if (pp == 6) {
                if (kt < 7) LOADSET(e0, e1, e2, e3, Kb + (size_t)((kt + 1) * 128) * 256 + colb, 256);
            } else {
                if (kt < 7) LOADSET(o0, o1, o2, o3, Kb + (size_t)((kt + 1) * 128) * 256 + 64 + colb, 256);
            }
            if (pp < 4) {
                // ---- S += Q_dc K_dc^T (64-wide d-chunk dc = pp), 16x16 ----
                __builtin_amdgcn_s_setprio(1);
#pragma unroll
                for (int c2 = 0; c2 < 2; c2++)
#pragma unroll
                    for (int f = 0; f < 8; f++) {
                        bf16x8_t kb = *(const bf16x8_t*)
                            &buf[(f * 16 + fr) * 64 + (((c2 * 4 + qd) ^ (fr & 7)) << 3)];
                        S[f] = __builtin_amdgcn_mfma_f32_16x16x32_bf16(qa[pp * 2 + c2], kb, S[f], 0, 0, 0);
                    }
                __builtin_amdgcn_s_setprio(0);
                if (pp == 3) {
                    // ---- online softmax, shuffle-free common path ----
                    float pmax[4], tsum[4];
#pragma unroll
                    for (int r = 0; r < 4; r++) {
                        float mx = S[0][r];
#pragma unroll
                        for (int f = 1; f < 8; f++) mx = fmaxf(mx, S[f][r]);
                        pmax[r] = mx;
                        tsum[r] = 0.0f;
                    }
                    bool okl = (pmax[0] - mrun[0] <= 8.0f) & (pmax[1] - mrun[1] <= 8.0f)
                             & (pmax[2] - mrun[2] <= 8.0f) & (pmax[3] - mrun[3] <= 8.0f);
                    const bool trig = !__all(okl);
                    float alpha[4] = {1.0f, 1.0f, 1.0f, 1.0f};
                    if (trig) {
#pragma unroll
                        for (int r = 0; r < 4; r++) {
                            float mx = pmax[r];
#pragma unroll
                            for (int o = 1; o < 16; o <<= 1) mx = fmaxf(mx, __shfl_xor(mx, o));
                            const float mnew = fmaxf(mrun[r], mx);
                            alpha[r] = __expf(mrun[r] - mnew);
                            mrun[r] = mnew;
                            lrun[r] *= alpha[r];
                        }
                    }
                    if (fr == 0) {
#pragma unroll
                        for (int r = 0; r < 4; r++) alS[w * 16 + qd * 4 + r] = alpha[r];
                    }
                    if (lane == 0) flS[w] = trig ? 1 : 0;
#pragma unroll
                    for (int f = 0; f < 8; f++) {
#pragma unroll
                        for (int r = 0; r < 4; r++) {
                            const float pv = __expf(S[f][r] - mrun[r]);
                            tsum[r] += pv;
                            Pg[((w & 1) * 16 + qd * 4 + r) * PG_S + f * 16 + fr] = (short)f2bf_bits(pv);
                        }
                    }
#pragma unroll
                    for (int r = 0; r < 4; r++) lrun[r] += tsum[r];
                }
            } else {
                // ---- O += P @ V, 32x32x16 (d-half h, kv-half kh) ----
                const int q4 = pp - 4, h = q4 >> 1, kh = q4 & 1;  // compile-time
                if (pp == 4) {
                    // cross-wave defer-max rescale (this kt's alphas)
                    if (flS[2 * qg] | flS[2 * qg + 1]) {
#pragma unroll
                        for (int r = 0; r < 16; r++) {
                            const int qrw = (r & 3) + 8 * (r >> 2) + 4 * hi;
                            const float a = alS[qg * 32 + qrw];
#pragma unroll
                            for (int i = 0; i < 4; i++) Op4[i][r] *= a;
                        }
                    }
                }
                __builtin_amdgcn_s_setprio(1);
#pragma unroll
                for (int kf = 0; kf < 4; kf++) {
                    const bf16x8_t pa = *(const bf16x8_t*)&Pg[l31 * PG_S + kh * 64 + kf * 16 + hi * 8];
#pragma unroll
                    for (int dt = 0; dt < 2; dt++) {
                        const bf16x8_t vb = *(const bf16x8_t*)
                            &buf[(dh * 64 + dt * 32 + l31) * 64 + (((kf * 2 + hi) ^ (l31 & 7)) << 3)];
                        Op4[h * 2 + dt] =
                            __builtin_amdgcn_mfma_f32_32x32x16_bf16(pa, vb, Op4[h * 2 + dt], 0, 0, 0);
                    }
                }
                __builtin_amdgcn_s_setprio(0);
            }
        }
    }
#undef LOADSET

    // ---- finalize: reduce per-lane lrun, share via LDS, store Msg ----
#pragma unroll
    for (int r = 0; r < 4; r++) {
#pragma unroll
        for (int o = 1; o < 16; o <<= 1) lrun[r] += __shfl_xor(lrun[r], o);
    }
    if (fr == 0) {
#pragma unroll
        for (int r = 0; r < 4; r++) lrS[w * 16 + qd * 4 + r] = lrun[r];
    }
    __syncthreads();
    float inv16[16];
#pragma unroll
    for (int r = 0; r < 16; r++) {
        const int qrw = (r & 3) + 8 * (r >> 2) + 4 * hi;
        inv16[r] = 1.0f / lrS[qg * 32 + qrw];
    }
    float* outB = Msg + ((size_t)p * 3 + m) * BND_ + (size_t)batch * N_ * D_
                + (size_t)(qt * 64 + qg * 32) * D_;
#pragma unroll
    for (int i = 0; i < 4; i++) {
        const int dcol = (i >> 1) * 128 + dh * 64 + (i & 1) * 32 + l31;
#pragma unroll
        for (int r = 0; r < 16; r++) {
            const int qrw = (r & 3) + 8 * (r >> 2) + 4 * hi;
            outB[(size_t)qrw * D_ + dcol] = Op4[i][r] * inv16[r];
        }
    }
}

// ---------------------------------------------------------------------------
// Weight convert+transpose, all 5 weights in one dispatch (z selects).
// ---------------------------------------------------------------------------
__global__ __launch_bounds__(256) void wt_transpose_kernel(
    const float* __restrict__ W0, const float* __restrict__ W1,
    const float* __restrict__ W2, const float* __restrict__ W3,
    const float* __restrict__ W4, __hip_bfloat16* __restrict__ out)
{
    const int z = blockIdx.z;
    const float* in = z == 0 ? W0 : z == 1 ? W1 : z == 2 ? W2 : z == 3 ? W3 : W4;
    __hip_bfloat16* o = out + (size_t)z * D_ * D_;
    __shared__ float t[32][33];
    const int r0 = blockIdx.x * 32, c0 = blockIdx.y * 32;
    const int tx = threadIdx.x & 31, ty = threadIdx.x >> 5;
#pragma unroll
    for (int k = 0; k < 4; k++) {
        int r = ty + k * 8;
        t[r][tx] = in[(size_t)(r0 + r) * D_ + (c0 + tx)];
    }
    __syncthreads();
#pragma unroll
    for (int k = 0; k < 4; k++) {
        int r = ty + k * 8;
        o[(size_t)(c0 + r) * D_ + (r0 + tx)] = __float2bfloat16(t[tx][r]);
    }
}

// all 3 modality inputs fp32 -> bf16, one dispatch
__global__ void cvt3_kernel(const float* __restrict__ x0, const float* __restrict__ x1,
                            const float* __restrict__ x2, __hip_bfloat16* __restrict__ dst)
{
    const int z = blockIdx.z;
    const float* s = z == 0 ? x0 : z == 1 ? x1 : x2;
    const long long i = (long long)blockIdx.x * 256 + threadIdx.x;
    dst[(size_t)z * BND_ + i] = __float2bfloat16(s[i]);
}

// ---------------------------------------------------------------------------
// Fused hypergraph prep: per-modality block does count -> scan(N) -> scan(M)
// -> fill, all counters/offsets in LDS. Replaces zero/count/scan/scan/fill
// (5 serial launches -> 1).
// ---------------------------------------------------------------------------
__global__ __launch_bounds__(1024) void hg_prep_kernel(
    const int* __restrict__ i0, const int* __restrict__ i1, const int* __restrict__ i2,
    int* __restrict__ NOffs, int* __restrict__ EOffs,
    float* __restrict__ Dinv, float* __restrict__ Bnorm,
    int* __restrict__ NOrd, int* __restrict__ EOrd)
{
    const int z = blockIdx.z;
    const int* nidx = z == 0 ? i0 : z == 1 ? i1 : i2;
    const int* eidx = nidx + C_;
    NOffs += z * (N_ + 1); EOffs += z * (M_ + 1);
    Dinv += z * N_; Bnorm += z * M_;
    NOrd += z * C_; EOrd += z * C_;

    __shared__ int ncnt[N_];
    __shared__ int ecnt[M_];
    __shared__ int tmp[N_];
    __shared__ int noff[N_ + 1];
    __shared__ int eoff[M_ + 1];

    const int t = threadIdx.x;
    ncnt[t] = 0;
    if (t < M_) ecnt[t] = 0;
    __syncthreads();
#pragma unroll
    for (int c = t; c < C_; c += 1024) {
        atomicAdd(&ncnt[nidx[c]], 1);
        atomicAdd(&ecnt[eidx[c]], 1);
    }
    __syncthreads();
    // scan N (Hillis-Steele, inclusive)
    const int vn = ncnt[t];
    tmp[t] = vn;
    __syncthreads();
    for (int o = 1; o < N_; o <<= 1) {
        int x = (t >= o) ? tmp[t - o] : 0;
        __syncthreads();
        tmp[t] += x;
        __syncthreads();
    }
    noff[t] = tmp[t] - vn;
    NOffs[t] = tmp[t] - vn;
    if (t == N_ - 1) { noff[N_] = tmp[t]; NOffs[N_] = tmp[t]; }
    Dinv[t] = (vn > 0) ? (1.0f / (float)vn) : 0.0f;
    __syncthreads();
    // scan M
    int ve = 0;
    if (t < M_) { ve = ecnt[t]; tmp[t] = ve; }
    __syncthreads();
    for (int o = 1; o < M_; o <<= 1) {
        int x = (t >= o && t < M_) ? tmp[t - o] : 0;
        __syncthreads();
        if (t < M_) tmp[t] += x;
        __syncthreads();
    }
    if (t < M_) {
        eoff[t] = tmp[t] - ve;
        EOffs[t] = tmp[t] - ve;
        Bnorm[t] = (ve > 0) ? (1.0f / (float)ve) : 0.0f;
        if (t == M_ - 1) { eoff[M_] = tmp[t]; EOffs[M_] = tmp[t]; }
    }
    // reset counters, fill ordered lists
    ncnt[t] = 0;
    if (t < M_) ecnt[t] = 0;
    __syncthreads();
#pragma unroll
    for (int c = t; c < C_; c += 1024) {
        const int nd = nidx[c], ed = eidx[c];
        const int p1 = atomicAdd(&ncnt[nd], 1);
        NOrd[noff[nd] + p1] = c;
        const int p2 = atomicAdd(&ecnt[ed], 1);
        EOrd[eoff[ed] + p2] = c;
    }
}

// s1/s2 from bf16 xp; one wave per (md,b,n)
__global__ __launch_bounds__(64) void hg_s12_kernel(
    const unsigned short* __restrict__ Xp, const float* __restrict__ att,
    float* __restrict__ s1, float* __restrict__ s2)
{
    const int z = blockIdx.z;
    const int bid = blockIdx.x;
    const int b = bid >> 10;
    const int n = bid & (N_ - 1);
    const int lane = threadIdx.x;
    const unsigned short* xr = Xp + (size_t)z * BND_ + (size_t)(b * N_ + n) * D_;
    const ushort4 u = ((const ushort4*)xr)[lane];
    const float4 a1 = ((const float4*)att)[lane];
    const float4 a2 = ((const float4*)(att + D_))[lane];
    float d1 = bf2f(u.x) * a1.x + bf2f(u.y) * a1.y + bf2f(u.z) * a1.z + bf2f(u.w) * a1.w;
    float d2 = bf2f(u.x) * a2.x + bf2f(u.y) * a2.y + bf2f(u.z) * a2.z + bf2f(u.w) * a2.w;
#pragma unroll
    for (int o = 32; o > 0; o >>= 1) { d1 += __shfl_down(d1, o); d2 += __shfl_down(d2, o); }
    if (lane == 0) { s1[z * NB_ + n * 16 + b] = d1; s2[z * NB_ + n * 16 + b] = d2; }
}

// edge_s2[m,b]: atomic-free, grid (M_,1,3), 16 pos x 16 b LDS reduce.
__global__ __launch_bounds__(256) void hg_edge_s2_kernel(
    const int* __restrict__ i0, const int* __restrict__ i1, const int* __restrict__ i2,
    const int* __restrict__ eoffs, const int* __restrict__ eord,
    const float* __restrict__ s2, float* __restrict__ edge_s2)
{
    const int z = blockIdx.z;
    const int* nidx = z == 0 ? i0 : z == 1 ? i1 : i2;
    eoffs += z * (M_ + 1); eord += z * C_;
    s2 += z * NB_; edge_s2 += (size_t)z * M_ * 16;

    const int m = blockIdx.x;
    const int pos = threadIdx.x >> 4;
    const int b = threadIdx.x & 15;
    const int base = eoffs[m];
    const int len = eoffs[m + 1] - base;
    float acc = 0.0f;
#pragma unroll 4
    for (int i = pos; i < len; i += 16) {
        int c = eord[base + i];
        acc += s2[nidx[c] * 16 + b];
    }
    __shared__ float red[16][16];
    red[pos][b] = acc;
    __syncthreads();
    for (int s = 8; s > 0; s >>= 1) {
        if (pos < s) red[pos][b] += red[pos + s][b];
        __syncthreads();
    }
    if (pos == 0) edge_s2[m * 16 + b] = red[0][b];
}

__global__ __launch_bounds__(256) void hg_node_softmax_kernel(
    const int* __restrict__ i0, const int* __restrict__ i1, const int* __restrict__ i2,
    const int* __restrict__ noffs, const int* __restrict__ nord,
    const float* __restrict__ s1, const float* __restrict__ edge_s2,
    float* __restrict__ ee, float* __restrict__ inv_sum)
{
    const int z = blockIdx.z;
    const int* eidx = (z == 0 ? i0 : z == 1 ? i1 : i2) + C_;
    noffs += z * (N_ + 1); nord += z * C_;
    s1 += z * NB_; edge_s2 += (size_t)z * M_ * 16;
    ee += (size_t)z * C_ * 16; inv_sum += z * NB_;

    const int n = blockIdx.x;
    const int base = noffs[n];
    const int len = noffs[n + 1] - base;
    if (len == 0) return;
    const int cp = threadIdx.x >> 4;
    const int b = threadIdx.x & 15;
    __shared__ float red[16][16];
    const float s1nb = s1[n * 16 + b];

    float mx = -1e30f;
    for (int i = cp; i < len; i += 16) {
        int c = nord[base + i];
        float e = s1nb + edge_s2[eidx[c] * 16 + b];
        e = e > 0.0f ? e : 0.2f * e;      // leaky_relu 0.2
        mx = fmaxf(mx, e);
    }
    red[cp][b] = mx;
    __syncthreads();
    for (int s = 8; s > 0; s >>= 1) {
        if (cp < s) red[cp][b] = fmaxf(red[cp][b], red[cp + s][b]);
        __syncthreads();
    }
    mx = red[0][b];
    __syncthreads();

    float sm = 0.0f;
    for (int i = cp; i < len; i += 16) {
        int c = nord[base + i];
        float e = s1nb + edge_s2[eidx[c] * 16 + b];
        e = e > 0.0f ? e : 0.2f * e;
        float ex = __expf(e - mx);
        ee[c * 16 + b] = ex;
        sm += ex;
    }
    red[cp][b] = sm;
    __syncthreads();
    for (int s = 8; s > 0; s >>= 1) {
        if (cp < s) red[cp][b] += red[cp + s][b];
        __syncthreads();
    }
    if (cp == 0) inv_sum[n * 16 + b] = 1.0f / (red[0][b] + 1e-16f);
}

// Pack sorted-order gather arrays (kills dependent chains in xedge/xnode).
__global__ __launch_bounds__(256) void hg_pack_kernel(
    const int* __restrict__ i0, const int* __restrict__ i1, const int* __restrict__ i2,
    const int* __restrict__ nord, const int* __restrict__ eord,
    const float* __restrict__ ee, const float* __restrict__ inv_sum,
    int* __restrict__ EmS, int* __restrict__ NnS,
    float* __restrict__ CoefN, float* __restrict__ CoefE)
{
    const int z = blockIdx.z;
    const int* nidx = z == 0 ? i0 : z == 1 ? i1 : i2;
    const int* eidx = nidx + C_;
    nord += z * C_; eord += z * C_;
    ee += (size_t)z * C_ * 16; inv_sum += z * NB_;
    EmS += z * C_; NnS += z * C_;
    CoefN += (size_t)z * C_ * 16; CoefE += (size_t)z * C_ * 16;

    const int gid = blockIdx.x * 256 + threadIdx.x;   // C*16
    const int i = gid >> 4, b = gid & 15;
    const int c1 = nord[i], c2 = eord[i];
    const int n1 = nidx[c1], n2 = nidx[c2];
    if (b == 0) { EmS[i] = eidx[c1]; NnS[i] = n2; }
    CoefN[i * 16 + b] = ee[c1 * 16 + b] * inv_sum[n1 * 16 + b];
    CoefE[i * 16 + b] = ee[c2 * 16 + b] * inv_sum[n2 * 16 + b];
}

// x_edge[m,b,:] via packed arrays.
__global__ __launch_bounds__(256) void hg_xedge_kernel(
    const int* __restrict__ eoffs, const int* __restrict__ NnS,
    const float* __restrict__ CoefE, const unsigned short* __restrict__ Xp,
    const float* __restrict__ Bnorm, float* __restrict__ x_edge)
{
    const int z = blockIdx.z;
    eoffs += z * (M_ + 1); NnS += z * C_;
    CoefE += (size_t)z * C_ * 16;
    const unsigned short* xp = Xp + (size_t)z * BND_;
    Bnorm += z * M_; x_edge += (size_t)z * M_ * B_ * D_;

    const int m = blockIdx.x >> 4;
    const int b = blockIdx.x & 15;
    const int d = threadIdx.x;
    const int base = eoffs[m];
    const int len = eoffs[m + 1] - base;
    float acc = 0.0f;
#pragma unroll 4
    for (int i = 0; i < len; i++) {
        const int nn = NnS[base + i];
        const float cf = CoefE[(size_t)(base + i) * 16 + b];
        acc += cf * bf2f(xp[(size_t)(b * N_ + nn) * D_ + d]);
    }
    x_edge[((size_t)(m * 16 + b)) * D_ + d] = Bnorm[m] * acc;
}

// h[b,n,:] via packed arrays.
__global__ __launch_bounds__(256) void hg_xnode_kernel(
    const int* __restrict__ noffs, const int* __restrict__ EmS,
    const float* __restrict__ CoefN, const float* __restrict__ x_edge,
    const float* __restrict__ Dinv, __hip_bfloat16* __restrict__ Hbf)
{
    const int z = blockIdx.z;
    noffs += z * (N_ + 1); EmS += z * C_;
    CoefN += (size_t)z * C_ * 16;
    x_edge += (size_t)z * M_ * B_ * D_; Dinv += z * N_;
    __hip_bfloat16* hbf = Hbf + (size_t)z * BND_;

    const int n = blockIdx.x >> 4;
    const int b = blockIdx.x & 15;
    const int d = threadIdx.x;
    const int base = noffs[n];
    const int len = noffs[n + 1] - base;
    float acc = 0.0f;
#pragma unroll 4
    for (int i = 0; i < len; i++) {
        const int em = EmS[base + i];
        const float cf = CoefN[(size_t)(base + i) * 16 + b];
        acc += cf * x_edge[((size_t)(em * 16 + b)) * D_ + d];
    }
    hbf[((size_t)(b * N_ + n)) * D_ + d] = __float2bfloat16(Dinv[n] * acc);
}

// ---------------------------------------------------------------------------
// Host
// ---------------------------------------------------------------------------
static inline void launch_gemm(hipStream_t s, dim3 grid,
                               const void* A0, const void* A1, int lda, long long sA,
                               const void* B0, const void* B1, int ldb, long long sB,
                               void* Cv, int ldc, long long sC, long long cOff, long long pieceCs,
                               int K, int kPiece, int zBatches,
                               float scale, const float* bias,
                               const float* a0, const float* a1, int epi)
{
    gemm_nt_kernel<<<grid, 256, 0, s>>>((const __hip_bfloat16*)A0, (const __hip_bfloat16*)A1,
                                        lda, sA,
                                        (const __hip_bfloat16*)B0, (const __hip_bfloat16*)B1,
                                        ldb, sB,
                                        Cv, ldc, sC, cOff, pieceCs, K, kPiece, zBatches,
                                        scale, bias, a0, a1, epi);
}

extern "C" void kernel_launch(void* const* d_in, const int* in_sizes, int n_in,
                              void* d_out, int out_size, void* d_ws, size_t ws_size,
                              hipStream_t stream)
{
    (void)in_sizes; (void)n_in; (void)out_size; (void)ws_size;

    const float* x0 = (const float*)d_in[0];
    const float* x1 = (const float*)d_in[1];
    const float* x2 = (const float*)d_in[2];
    const int* h0 = (const int*)d_in[3];
    const int* h1 = (const int*)d_in[4];
    const int* h2 = (const int*)d_in[5];
    const float* W_hg  = (const float*)d_in[6];
    const float* att_hg= (const float*)d_in[7];
    const float* WQ = (const float*)d_in[8];
    const float* bQ = (const float*)d_in[9];
    const float* WK = (const float*)d_in[10];
    const float* bK = (const float*)d_in[11];
    const float* WV = (const float*)d_in[12];
    const float* bV = (const float*)d_in[13];
    const float* WO = (const float*)d_in[14];
    const float* bO = (const float*)d_in[15];
    float* outp = (float*)d_out;

    char* ws = (char*)d_ws;
    size_t off = 0;
    auto take = [&](size_t bytes) { size_t r = off; off += (bytes + 255) & ~(size_t)255; return r; };

    const size_t oWt   = take((size_t)5 * D_ * D_ * 2);          // 0.63 MB
    const size_t oHbf  = take((size_t)3 * BND_ * 2);             // 24 MB
    const size_t oKall = take((size_t)3 * BND_ * 2);             // 24 MB
    const size_t oVt   = take((size_t)3 * BND_ * 2);             // 24 MB
    const size_t oQall = take((size_t)3 * BND_ * 2);             // 24 MB
    const size_t oBIG  = take((size_t)6 * BND_ * 4);             // 96 MB: Xc+Xp | Msg(2)
    const size_t oXe   = take((size_t)3 * M_ * B_ * D_ * 4);     // 6 MB
    const size_t oEE   = take((size_t)3 * C_ * 16 * 4);
    const size_t oCoefN= take((size_t)3 * C_ * 16 * 4);
    const size_t oCoefE= take((size_t)3 * C_ * 16 * 4);
    const size_t oEmS  = take((size_t)3 * C_ * 4);
    const size_t oNnS  = take((size_t)3 * C_ * 4);
    const size_t oS1   = take((size_t)3 * NB_ * 4);
    const size_t oS2   = take((size_t)3 * NB_ * 4);
    const size_t oInv  = take((size_t)3 * NB_ * 4);
    const size_t oEs2  = take((size_t)3 * M_ * 16 * 4);
    const size_t oNOffs= take((size_t)3 * (N_ + 1) * 4);
    const size_t oEOffs= take((size_t)3 * (M_ + 1) * 4);
    const size_t oNOrd = take((size_t)3 * C_ * 4);
    const size_t oEOrd = take((size_t)3 * C_ * 4);
    const size_t oDinv = take((size_t)3 * N_ * 4);
    const size_t oBnorm= take((size_t)3 * M_ * 4);

    __hip_bfloat16* Wt   = (__hip_bfloat16*)(ws + oWt);
    __hip_bfloat16* Hbf  = (__hip_bfloat16*)(ws + oHbf);
    __hip_bfloat16* Kall = (__hip_bfloat16*)(ws + oKall);
    __hip_bfloat16* Vt   = (__hip_bfloat16*)(ws + oVt);
    __hip_bfloat16* Qall = (__hip_bfloat16*)(ws + oQall);
    __hip_bfloat16* Xc   = (__hip_bfloat16*)(ws + oBIG);
    __hip_bfloat16* Xp   = (__hip_bfloat16*)(ws + oBIG + (size_t)3 * BND_ * 2);
    float* Msg  = (float*)(ws + oBIG);
    float* Xe   = (float*)(ws + oXe);
    float* EE   = (float*)(ws + oEE);
    float* CoefN= (float*)(ws + oCoefN);
    float* CoefE= (float*)(ws + oCoefE);
    int*   EmS  = (int*)(ws + oEmS);
    int*   NnS  = (int*)(ws + oNnS);
    float* S1f  = (float*)(ws + oS1);
    float* S2f  = (float*)(ws + oS2);
    float* Inv  = (float*)(ws + oInv);
    float* Es2  = (float*)(ws + oEs2);
    int*   NOffs = (int*)(ws + oNOffs);
    int*   EOffs = (int*)(ws + oEOffs);
    int*   NOrd  = (int*)(ws + oNOrd);
    int*   EOrd  = (int*)(ws + oEOrd);
    float* Dinv  = (float*)(ws + oDinv);
    float* Bnorm = (float*)(ws + oBnorm);

    const int WN = D_ * D_;
    __hip_bfloat16* WtHG = Wt;
    __hip_bfloat16* WtQ  = Wt + (size_t)WN;
    __hip_bfloat16* WtK  = Wt + (size_t)2 * WN;
    __hip_bfloat16* WtV  = Wt + (size_t)3 * WN;
    __hip_bfloat16* WtO  = Wt + (size_t)4 * WN;

    // -------- Phase 0: weights (one dispatch) -------------------------------
    wt_transpose_kernel<<<dim3(8, 8, 5), 256, 0, stream>>>(W_hg, WQ, WK, WV, WO, Wt);

    // -------- Phase 1: hypergraph conv, all modalities batched --------------
    cvt3_kernel<<<dim3((unsigned)(BND_ / 256), 1, 3), 256, 0, stream>>>(x0, x1, x2, Xc);
    hg_prep_kernel<<<dim3(1, 1, 3), 1024, 0, stream>>>(h0, h1, h2, NOffs, EOffs,
                                                       Dinv, Bnorm, NOrd, EOrd);
    launch_gemm(stream, dim3(BN_ / 128, D_ / 128, 3),
                Xc, Xc, D_, BND_, WtHG, WtHG, D_, 0,
                Xp, D_, BND_, 0, 0, D_, D_, 3,
                1.0f, nullptr, nullptr, nullptr, 1);
    hg_s12_kernel<<<dim3(BN_, 1, 3), 64, 0, stream>>>((const unsigned short*)Xp, att_hg, S1f, S2f);
    hg_edge_s2_kernel<<<dim3(M_, 1, 3), 256, 0, stream>>>(h0, h1, h2, EOffs, EOrd, S2f, Es2);
    hg_node_softmax_kernel<<<dim3(N_, 1, 3), 256, 0, stream>>>(h0, h1, h2, NOffs, NOrd,
                                                               S1f, Es2, EE, Inv);
    hg_pack_kernel<<<dim3(C_ * 16 / 256, 1, 3), 256, 0, stream>>>(h0, h1, h2, NOrd, EOrd,
                                                                  EE, Inv, EmS, NnS, CoefN, CoefE);
    hg_xedge_kernel<<<dim3(M_ * B_, 1, 3), 256, 0, stream>>>(EOffs, NnS, CoefE,
                                                             (const unsigned short*)Xp, Bnorm, Xe);
    hg_xnode_kernel<<<dim3(N_ * B_, 1, 3), 256, 0, stream>>>(NOffs, EmS, CoefN, Xe, Dinv, Hbf);

    // -------- Phase 2: K, V, Q for all 3 modalities -------------------------
    launch_gemm(stream, dim3(3 * BN_ / 128, D_ / 128, 1),
                Hbf, Hbf, D_, 0, WtK, WtK, D_, 0,
                Kall, D_, 0, 0, 0, D_, D_, 1,
                1.0f, bK, nullptr, nullptr, 1);
    // V: direct transposed store into Vt (epi=5), no separate transpose pass.
    launch_gemm(stream, dim3(3 * BN_ / 128, D_ / 128, 1),
                Hbf, Hbf, D_, 0, WtV, WtV, D_, 0,
                Vt, D_, 0, 0, 0, D_, D_, 1,
                1.0f, bV, nullptr, nullptr, 5);
    launch_gemm(stream, dim3(3 * BN_ / 128, D_ / 128, 1),
                Hbf, Hbf, D_, 0, WtQ, WtQ, D_, 0,
                Qall, D_, 0, 0, 0, D_, D_, 1,
                0.0625f, bQ, nullptr, nullptr, 4);

    // -------- Phase 3: fused flash attention + output -----------------------
    flash_attn_kernel<<<dim3(1536, 1, 1), 256, 0, stream>>>(Qall, Kall, Vt, Msg);
    launch_gemm(stream, dim3(BN_ / 128, D_ / 128, 3),
                Hbf, Hbf, D_, BND_, WtO, WtO, D_, 0,
                outp, D_, BND_, 0, 0, D_, D_, 3,
                1.0f, bO, Msg, Msg + (size_t)3 * BND_, 2);
}

// Round 9
// 619.711 us; speedup vs baseline: 1.1345x; 1.1345x over previous
//
#include <hip/hip_runtime.h>
#include <hip/hip_bf16.h>
#include <stdint.h>

// ---------------------------------------------------------------------------
// B=16, N=1024, D=256, M=128, C=8192. fp32 in/out, bf16 MFMA internally.
// Output: 3 x [B,N,D] fp32 concatenated.
// Attention fully fused (flash-style). NOTE: all register-array indices in the
// flash kernel MUST be compile-time (runtime index -> scratch spill, R10: 2.3GB
// of spill writes, 7x regression).
// R1: flash 64-wide chunks, 8 phases/kt, partner split on grid.
// R2: 2-phase-deep register prefetch + s_setprio around MFMA clusters.
// R3: XCD-aware 1-D grid swizzle (FETCH 418->74MB).
// R4: __launch_bounds__(256,2) -> 2 waves/SIMD; T13 defer-max.
// R5: PV -> mfma_32x32x16 via wave-pair shared P; shuffle-free softmax.
// R6 (REVERTED): direct-global K gather (512B stride = 16 lines/instr, 2.3x).
// R7: FA_S->64 + XOR chunk swizzle; conflicts 12.6M->6.3M. Flash ~91%
//     LDS-pipe-busy - near its structural floor.
// R8: hg_prep fusion + epi=5 transposed V store (KEPT: non-flash -6us).
//     PG_S 136->132 REVERTED here: 132 shorts = 264B is not 16B-aligned ->
//     odd Pg rows broke ds_read_b128 into split reads (flash 173->236, with
//     conflicts byte-identical -- the residual 6.3M was never in Pg).
// R9: PG_S back to 136 (aligned; 4-way on 64 pa reads/block-kt is minimal
//     under the 16B-alignment constraint). K/V/Q GEMMs fused into ONE
//     qkv_gemm_kernel dispatch (z selects weight+epilogue): -2 launches,
//     768->2304 resident blocks.
// ---------------------------------------------------------------------------

namespace {
constexpr int B_ = 16;
constexpr int N_ = 1024;
constexpr int D_ = 256;
constexpr int M_ = 128;
constexpr int C_ = 8192;
constexpr int BN_ = B_ * N_;                       // 16384
constexpr long long BND_ = (long long)BN_ * D_;    // 4,194,304 elems
constexpr int NB_ = N_ * B_;                       // 16384
constexpr int LDA_S = 40;                          // K-loop LDS stride (shorts)
constexpr int EPI_S = 68;                          // epilogue LDS stride (floats)
constexpr int PG_S = 136;                          // flash P stride: 272B, 16B-aligned
}

typedef short bf16x8_t __attribute__((ext_vector_type(8)));
typedef float f32x4_t __attribute__((ext_vector_type(4)));
typedef float f32x16_t __attribute__((ext_vector_type(16)));
typedef unsigned short u16x8_t __attribute__((ext_vector_type(8)));

#define DEV static __device__ __forceinline__
DEV float bf2f(unsigned short u) { return __uint_as_float((unsigned)u << 16); }
DEV unsigned short f2bf_bits(float x) { return __builtin_bit_cast(unsigned short, __float2bfloat16(x)); }

// ---------------------------------------------------------------------------
// NT bf16 MFMA GEMM, 128x128 tile, BK=32, 4 waves, LDS-transposed epilogue.
// epi: 0 = fp32 C = v (v = acc*scale)
//      1 = bf16 C = v + bias[col]
//      2 = fp32 C = relu(v + bias[col] + add0[idx] + add1[idx])
//      4 = bf16 C = v + bias[col]*scale      (i.e. (acc+bias)*scale)
// ---------------------------------------------------------------------------
__global__ __launch_bounds__(256) void gemm_nt_kernel(
    const __hip_bfloat16* __restrict__ A0, const __hip_bfloat16* __restrict__ A1,
    int lda, long long sA,
    const __hip_bfloat16* __restrict__ B0, const __hip_bfloat16* __restrict__ B1,
    int ldb, long long sB,
    void* __restrict__ Cv, int ldc, long long sC, long long cOff, long long pieceCs,
    int K, int kPiece, int zBatches,
    float scale, const float* __restrict__ bias,
    const float* __restrict__ add0, const float* __restrict__ add1,
    int epi)
{
    __shared__ __align__(16) char smem[20480];
    short* smA = (short*)smem;
    short* smB = (short*)(smem + 10240);

    const int tid = threadIdx.x;
    const int wid = tid >> 6;
    const int lane = tid & 63;
    const int z = blockIdx.z;
    const int batch = z % zBatches;
    const int rem = z / zBatches;
    const int pi = rem & 1;
    const int kh = rem >> 1;

    const short* Ab = (const short*)(pi ? A1 : A0) + (size_t)batch * sA
                    + (size_t)blockIdx.x * 128 * lda + (size_t)kh * kPiece;
    const short* Bb = (const short*)(pi ? B1 : B0) + (size_t)batch * sB
                    + (size_t)blockIdx.y * 128 * ldb + (size_t)kh * kPiece;

    const int wm = (wid >> 1) * 64;
    const int wn = (wid & 1) * 64;
    const int fr = lane & 15;
    const int kq = (lane >> 4) * 8;
    const int sr = tid >> 2;
    const int sc = (tid & 3) * 8;

    f32x4_t acc[4][4] = {};
    int4 avv[2], bvv[2];
#pragma unroll
    for (int h = 0; h < 2; h++) {
        const int row = h * 64 + sr;
        avv[h] = *(const int4*)(Ab + (size_t)row * lda + sc);
        bvv[h] = *(const int4*)(Bb + (size_t)row * ldb + sc);
    }

    for (int k0 = 0; k0 < K; k0 += 32) {
        __syncthreads();
#pragma unroll
        for (int h = 0; h < 2; h++) {
            const int row = h * 64 + sr;
            *(int4*)&smA[row * LDA_S + sc] = avv[h];
            *(int4*)&smB[row * LDA_S + sc] = bvv[h];
        }
        __syncthreads();

        const int kn = k0 + 32;
        if (kn < K) {
#pragma unroll
            for (int h = 0; h < 2; h++) {
                const int row = h * 64 + sr;
                avv[h] = *(const int4*)(Ab + (size_t)row * lda + (kn + sc));
                bvv[h] = *(const int4*)(Bb + (size_t)row * ldb + (kn + sc));
            }
        }

        bf16x8_t af[4], bfv[4];
#pragma unroll
        for (int i = 0; i < 4; i++)
            af[i] = *(const bf16x8_t*)&smA[(wm + i * 16 + fr) * LDA_S + kq];
#pragma unroll
        for (int j = 0; j < 4; j++)
            bfv[j] = *(const bf16x8_t*)&smB[(wn + j * 16 + fr) * LDA_S + kq];
#pragma unroll
        for (int i = 0; i < 4; i++)
#pragma unroll
            for (int j = 0; j < 4; j++)
                acc[i][j] = __builtin_amdgcn_mfma_f32_16x16x32_bf16(af[i], bfv[j], acc[i][j], 0, 0, 0);
    }

    const int r_ = lane >> 4;
    float* lts = (float*)smem + wid * (16 * EPI_S);
#pragma unroll
    for (int i = 0; i < 4; i++) {
        __syncthreads();
#pragma unroll
        for (int j = 0; j < 4; j++)
#pragma unroll
            for (int r = 0; r < 4; r++)
                lts[(r_ * 4 + r) * EPI_S + j * 16 + fr] = acc[i][j][r] * scale;
        __syncthreads();
#pragma unroll
        for (int t = 0; t < 4; t++) {
            const int lrow = t * 4 + r_;
            const f32x4_t v4 = *(const f32x4_t*)&lts[lrow * EPI_S + fr * 4];
            const int row = blockIdx.x * 128 + wm + i * 16 + lrow;
            const int col = blockIdx.y * 128 + wn + fr * 4;
            const size_t idx = (size_t)batch * sC + (size_t)row * ldc + col;
            const size_t gidx = (size_t)cOff + (size_t)rem * pieceCs + idx;
            if (epi == 0) {
                *(f32x4_t*)((float*)Cv + gidx) = v4;
            } else if (epi == 1 || epi == 4) {
                f32x4_t bb = {0.f, 0.f, 0.f, 0.f};
                if (bias) bb = *(const f32x4_t*)(bias + col);
                const float bs = (epi == 4) ? scale : 1.0f;
                ushort4 pk;
                pk.x = f2bf_bits(v4[0] + bb[0] * bs);
                pk.y = f2bf_bits(v4[1] + bb[1] * bs);
                pk.z = f2bf_bits(v4[2] + bb[2] * bs);
                pk.w = f2bf_bits(v4[3] + bb[3] * bs);
                *(ushort4*)((unsigned short*)Cv + gidx) = pk;
            } else {
                const f32x4_t bb = *(const f32x4_t*)(bias + col);
                const f32x4_t m0 = *(const f32x4_t*)(add0 + idx);
                const f32x4_t m1 = *(const f32x4_t*)(add1 + idx);
                f32x4_t o;
#pragma unroll
                for (int k = 0; k < 4; k++) {
                    float v = v4[k] + bb[k] + m0[k] + m1[k];
                    o[k] = v > 0.0f ? v : 0.0f;
                }
                *(f32x4_t*)((float*)Cv + gidx) = o;
            }
        }
    }
}

// ---------------------------------------------------------------------------
// Fused K/V/Q projection: one dispatch, grid (3*BN/128, D/128, 3).
// z=0: Kall = bf16(H @ WtK + bK)
// z=1: Vt   = transposed bf16 store (epi5 pattern): Vt[mb][d][n]
// z=2: Qall = bf16((H @ WtQ + bQ) * 1/16)
// ---------------------------------------------------------------------------
__global__ __launch_bounds__(256) void qkv_gemm_kernel(
    const __hip_bfloat16* __restrict__ Hbf, const __hip_bfloat16* __restrict__ Wt,
    const float* __restrict__ bQ, const float* __restrict__ bK, const float* __restrict__ bV,
    __hip_bfloat16* __restrict__ Qall, __hip_bfloat16* __restrict__ Kall,
    __hip_bfloat16* __restrict__ Vt)
{
    __shared__ __align__(16) char smem[20480];
    short* smA = (short*)smem;
    short* smB = (short*)(smem + 10240);

    const int tid = threadIdx.x;
    const int wid = tid >> 6;
    const int lane = tid & 63;
    const int z = blockIdx.z;                     // 0=K 1=V 2=Q
    const int WN = D_ * D_;
    // Wt layout: [W_hg, WQ, WK, WV, WO]
    const short* Bb = (const short*)Wt + (size_t)(z == 0 ? 2 : z == 1 ? 3 : 1) * WN
                    + (size_t)blockIdx.y * 128 * D_;
    const float* bias = z == 0 ? bK : z == 1 ? bV : bQ;
    const short* Ab = (const short*)Hbf + (size_t)blockIdx.x * 128 * D_;

    const int wm = (wid >> 1) * 64;
    const int wn = (wid & 1) * 64;
    const int fr = lane & 15;
    const int kq = (lane >> 4) * 8;
    const int sr = tid >> 2;
    const int sc = (tid & 3) * 8;

    f32x4_t acc[4][4] = {};
    int4 avv[2], bvv[2];
#pragma unroll
    for (int h = 0; h < 2; h++) {
        const int row = h * 64 + sr;
        avv[h] = *(const int4*)(Ab + (size_t)row * D_ + sc);
        bvv[h] = *(const int4*)(Bb + (size_t)row * D_ + sc);
    }

    for (int k0 = 0; k0 < D_; k0 += 32) {
        __syncthreads();
#pragma unroll
        for (int h = 0; h < 2; h++) {
            const int row = h * 64 + sr;
            *(int4*)&smA[row * LDA_S + sc] = avv[h];
            *(int4*)&smB[row * LDA_S + sc] = bvv[h];
        }
        __syncthreads();

        const int kn = k0 + 32;
        if (kn < D_) {
#pragma unroll
            for (int h = 0; h < 2; h++) {
                const int row = h * 64 + sr;
                avv[h] = *(const int4*)(Ab + (size_t)row * D_ + (kn + sc));
                bvv[h] = *(const int4*)(Bb + (size_t)row * D_ + (kn + sc));
            }
        }

        bf16x8_t af[4], bfv[4];
#pragma unroll
        for (int i = 0; i < 4; i++)
            af[i] = *(const bf16x8_t*)&smA[(wm + i * 16 + fr) * LDA_S + kq];
#pragma unroll
        for (int j = 0; j < 4; j++)
            bfv[j] = *(const bf16x8_t*)&smB[(wn + j * 16 + fr) * LDA_S + kq];
#pragma unroll
        for (int i = 0; i < 4; i++)
#pragma unroll
            for (int j = 0; j < 4; j++)
                acc[i][j] = __builtin_amdgcn_mfma_f32_16x16x32_bf16(af[i], bfv[j], acc[i][j], 0, 0, 0);
    }

    const int r_ = lane >> 4;

    if (z == 1) {
        // transposed store into Vt: lane col = fr (fixed), 4 consecutive rows.
#pragma unroll
        for (int i = 0; i < 4; i++) {
            const int row = blockIdx.x * 128 + wm + i * 16 + r_ * 4;
            const int mb = row >> 10;
            const int nl = row & 1023;
#pragma unroll
            for (int j = 0; j < 4; j++) {
                const int col = blockIdx.y * 128 + wn + j * 16 + fr;
                const float bb = bias[col];
                ushort4 pk;
                pk.x = f2bf_bits(acc[i][j][0] + bb);
                pk.y = f2bf_bits(acc[i][j][1] + bb);
                pk.z = f2bf_bits(acc[i][j][2] + bb);
                pk.w = f2bf_bits(acc[i][j][3] + bb);
                *(ushort4*)((unsigned short*)Vt + ((size_t)mb * D_ + col) * 1024 + nl) = pk;
            }
        }
        return;
    }

    const float oscale = (z == 2) ? 0.0625f : 1.0f;
    unsigned short* Cv = (unsigned short*)(z == 0 ? Kall : Qall);
    float* lts = (float*)smem + wid * (16 * EPI_S);
#pragma unroll
    for (int i = 0; i < 4; i++) {
        __syncthreads();
#pragma unroll
        for (int j = 0; j < 4; j++)
#pragma unroll
            for (int r = 0; r < 4; r++)
                lts[(r_ * 4 + r) * EPI_S + j * 16 + fr] = acc[i][j][r];
        __syncthreads();
#pragma unroll
        for (int t = 0; t < 4; t++) {
            const int lrow = t * 4 + r_;
            const f32x4_t v4 = *(const f32x4_t*)&lts[lrow * EPI_S + fr * 4];
            const int row = blockIdx.x * 128 + wm + i * 16 + lrow;
            const int col = blockIdx.y * 128 + wn + fr * 4;
            const f32x4_t bb = *(const f32x4_t*)(bias + col);
            ushort4 pk;
            pk.x = f2bf_bits((v4[0] + bb[0]) * oscale);
            pk.y = f2bf_bits((v4[1] + bb[1]) * oscale);
            pk.z = f2bf_bits((v4[2] + bb[2]) * oscale);
            pk.w = f2bf_bits((v4[3] + bb[3]) * oscale);
            *(ushort4*)(Cv + (size_t)row * D_ + col) = pk;
        }
    }
}

// ---------------------------------------------------------------------------
// Fused flash attention. 1-D grid of 1536 slots, XCD-swizzled (R3).
// Block = 64 Q-rows of one (m,batch,partner). Per kv-tile kt: 8 phases of
// 128x64 bf16 chunks (4 K d-chunks, then 4 V chunks) into 2x16KB ping-pong;
// ONE barrier per phase, 2-deep register prefetch.
// LDS layout: linear [128][64] shorts with XOR chunk swizzle c' = c ^ (row&7)
// on write and both reads. Pg stride PG_S=136 (272B, 16B-aligned; do NOT use
// non-multiple-of-8 strides: 132 broke ds_read_b128 -> split reads, R8).
// QK^T: 16x16x32, wave w owns q-rows w*16+[0,16).
// PV:   32x32x16, wave-pair shares P; wave (qg,dh) owns 32q x {dh*64 cols}.
// Softmax: per-lane partial max + __all trigger; lrun per-lane, reduced at
// epilogue; defer-max rescale at vp==0 via LDS alpha array.
// Msg[p][m][b][n][d] fp32 = softmax(Q_m K_p^T /16) @ V_p
// ---------------------------------------------------------------------------
__global__ __launch_bounds__(256, 2) void flash_attn_kernel(
    const __hip_bfloat16* __restrict__ Qall,   // [3][16][1024][256] bf16, pre-scaled by 1/16
    const __hip_bfloat16* __restrict__ Kall,   // [3][16][1024][256] bf16
    const __hip_bfloat16* __restrict__ Vt,     // [3][16][256][1024] bf16
    float* __restrict__ Msg)                   // [2][3][16][1024][256] fp32
{
    __shared__ __align__(16) short smKV[2][128 * 64];    // 2 x 16384 B ping-pong
    __shared__ __align__(16) short smP2[2][32 * PG_S];   // wave-pair shared P
    __shared__ float lrS[64];
    __shared__ float alS[64];
    __shared__ int   flS[4];

    const int tid = threadIdx.x;
    const int w = tid >> 6;
    const int lane = tid & 63;
    const int fr = lane & 15;
    const int qd = lane >> 4;
    const int l31 = lane & 31;
    const int hi = lane >> 5;
    const int qg = w >> 1;           // PV q-group (rows qg*32 + [0,32))
    const int dh = w & 1;            // PV d-subcolumn selector

    // XCD-aware decode: slot -> (qt, batch, zz). Bijective on [0,1536).
    const int slot = blockIdx.x;
    const int xcd = slot & 7;
    const int t_ = slot >> 3;
    const int qt = t_ & 15;
    const int gh = t_ >> 4;          // g/8, 0..11
    const int g = gh * 8 + xcd;      // group = batch + 16*zz, 0..95
    const int batch = g & 15;
    const int zz = g >> 4;           // 0..5
    const int m = zz >> 1;
    const int p = zz & 1;
    const int pn = (p == 0) ? (m == 0 ? 1 : 0) : (m == 2 ? 1 : 2);

    short* Pg = smP2[qg];            // [32][PG_S]

    // Q fragments: A[m=fr][k=qd*8+j] for 8 d-chunks, wave rows qt*64+w*16+fr
    const size_t qrow = ((size_t)(m * 16 + batch) * 1024) + qt * 64 + w * 16 + fr;
    const short* qp = (const short*)Qall + qrow * 256 + qd * 8;
    bf16x8_t qa[8];
#pragma unroll
    for (int c = 0; c < 8; c++) qa[c] = *(const bf16x8_t*)(qp + c * 32);

    const short* Kb = (const short*)Kall + ((size_t)(pn * 16 + batch) * 1024) * 256;
    const short* Vb = (const short*)Vt + ((size_t)(pn * 16 + batch) * 256) * 1024;

    const int row0 = tid >> 2;            // staging row 0..63 (plus +64)
    const int row1 = row0 + 64;
    const int colb = (tid & 3) * 16;      // global staging short-col (2 int4/row)
    // swizzled LDS chunk offsets (shorts) for this lane's two 16B chunks
    const int swkey = (tid >> 2) & 7;
    const int cA8 = (((tid & 3) * 2) ^ swkey) * 8;
    const int cB8 = (((tid & 3) * 2 + 1) ^ swkey) * 8;

    f32x16_t Op4[4] = {};                 // O[32q x 32d] tiles: i = h*2+dt
    float mrun[4] = {-1e30f, -1e30f, -1e30f, -1e30f};
    float lrun[4] = {0.f, 0.f, 0.f, 0.f}; // PER-LANE partial sums

#define LOADSET(p0, p1, p2, p3, base, stride)                                  \
    do {                                                                       \
        const short* _b = (base);                                              \
        p0 = *(const int4*)(_b + (size_t)row0 * (stride));                     \
        p1 = *(const int4*)(_b + (size_t)row0 * (stride) + 8);                 \
        p2 = *(const int4*)(_b + (size_t)row1 * (stride));                     \
        p3 = *(const int4*)(_b + (size_t)row1 * (stride) + 8);                 \
    } while (0)

    // prologue: phase 0 (K dc=0) into stE, phase 1 (K dc=1) into stO
    int4 e0, e1, e2, e3, o0, o1, o2, o3;
    LOADSET(e0, e1, e2, e3, Kb + colb, 256);
    LOADSET(o0, o1, o2, o3, Kb + 64 + colb, 256);

    for (int kt = 0; kt < 8; kt++) {
        f32x4_t S[8] = {};
#pragma unroll
        for (int pp = 0; pp < 8; pp++) {               // COMPILE-TIME phases
            short* buf = smKV[pp & 1];                 // kt*8 even -> pp&1
            if ((pp & 1) == 0) {
                *(int4*)&buf[row0 * 64 + cA8] = e0;
                *(int4*)&buf[row0 * 64 + cB8] = e1;
                *(int4*)&buf[row1 * 64 + cA8] = e2;
                *(int4*)&buf[row1 * 64 + cB8] = e3;
            } else {
                *(int4*)&buf[row0 * 64 + cA8] = o0;
                *(int4*)&buf[row0 * 64 + cB8] = o1;
                *(int4*)&buf[row1 * 64 + cA8] = o2;
                *(int4*)&buf[row1 * 64 + cB8] = o3;
            }
            __syncthreads();
            // issue loads for phase pp+2 (into the set just drained to LDS).
            // phase->data map: ph 0..3 = K d-chunk ph of kt; ph 4..7 = V chunk
            // q=ph-4 (h=q>>1 d-half, kh=q&1 kv-half) of kt.
            if (pp == 0) {
                LOADSET(e0, e1, e2, e3, Kb + (size_t)(kt * 128) * 256 + 128 + colb, 256);
            } else if (pp == 1) {
                LOADSET(o0, o1, o2, o3, Kb + (size_t)(kt * 128) * 256 + 192 + colb, 256);
            } else if (pp == 2) {
                LOADSET(e0, e1, e2, e3, Vb + (size_t)kt * 128 + colb, 1024);
            } else if (pp == 3) {
                LOADSET(o0, o1, o2, o3, Vb + (size_t)kt * 128 + 64 + colb, 1024);
            } else if (pp == 4) {
                LOADSET(e0, e1, e2, e3, Vb + (size_t)128 * 1024 + kt * 128 + colb, 1024);
            } else if (pp == 5) {
                LOADSET(o0, o1, o2, o3, Vb + (size_t)128 * 1024 + kt * 128 + 64 + colb, 1024);
            } else if (pp == 6) {
                if (kt < 7) LOADSET(e0, e1, e2, e3, Kb + (size_t)((kt + 1) * 128) * 256 + colb, 256);
            } else {
                if (kt < 7) LOADSET(o0, o1, o2, o3, Kb + (size_t)((kt + 1) * 128) * 256 + 64 + colb, 256);
            }
            if (pp < 4) {
                // ---- S += Q_dc K_dc^T (64-wide d-chunk dc = pp), 16x16 ----
                __builtin_amdgcn_s_setprio(1);
#pragma unroll
                for (int c2 = 0; c2 < 2; c2++)
#pragma unroll
                    for (int f = 0; f < 8; f++) {
                        bf16x8_t kb = *(const bf16x8_t*)
                            &buf[(f * 16 + fr) * 64 + (((c2 * 4 + qd) ^ (fr & 7)) << 3)];
                        S[f] = __builtin_amdgcn_mfma_f32_16x16x32_bf16(qa[pp * 2 + c2], kb, S[f], 0, 0, 0);
                    }
                __builtin_amdgcn_s_setprio(0);
                if (pp == 3) {
                    // ---- online softmax, shuffle-free common path ----
                    float pmax[4], tsum[4];
#pragma unroll
                    for (int r = 0; r < 4; r++) {
                        float mx = S[0][r];
#pragma unroll
                        for (int f = 1; f < 8; f++) mx = fmaxf(mx, S[f][r]);
                        pmax[r] = mx;
                        tsum[r] = 0.0f;
                    }
                    bool okl = (pmax[0] - mrun[0] <= 8.0f) & (pmax[1] - mrun[1] <= 8.0f)
                             & (pmax[2] - mrun[2] <= 8.0f) & (pmax[3] - mrun[3] <= 8.0f);
                    const bool trig = !__all(okl);
                    float alpha[4] = {1.0f, 1.0f, 1.0f, 1.0f};
                    if (trig) {
#pragma unroll
                        for (int r = 0; r < 4; r++) {
                            float mx = pmax[r];
#pragma unroll
                            for (int o = 1; o < 16; o <<= 1) mx = fmaxf(mx, __shfl_xor(mx, o));
                            const float mnew = fmaxf(mrun[r], mx);
                            alpha[r] = __expf(mrun[r] - mnew);
                            mrun[r] = mnew;
                            lrun[r] *= alpha[r];
                        }
                    }
                    if (fr == 0) {
#pragma unroll
                        for (int r = 0; r < 4; r++) alS[w * 16 + qd * 4 + r] = alpha[r];
                    }
                    if (lane == 0) flS[w] = trig ? 1 : 0;
#pragma unroll
                    for (int f = 0; f < 8; f++) {
#pragma unroll
                        for (int r = 0; r < 4; r++) {
                            const float pv = __expf(S[f][r] - mrun[r]);
                            tsum[r] += pv;
                            Pg[((w & 1) * 16 + qd * 4 + r) * PG_S + f * 16 + fr] = (short)f2bf_bits(pv);
                        }
                    }
#pragma unroll
                    for (int r = 0; r < 4; r++) lrun[r] += tsum[r];
                }
            } else {
                // ---- O += P @ V, 32x32x16 (d-half h, kv-half kh) ----
                const int q4 = pp - 4, h = q4 >> 1, kh = q4 & 1;  // compile-time
                if (pp == 4) {
                    // cross-wave defer-max rescale (this kt's alphas)
                    if (flS[2 * qg] | flS[2 * qg + 1]) {
#pragma unroll
                        for (int r = 0; r < 16; r++) {
                            const int qrw = (r & 3) + 8 * (r >> 2) + 4 * hi;
                            const float a = alS[qg * 32 + qrw];
#pragma unroll
                            for (int i = 0; i < 4; i++) Op4[i][r] *= a;
                        }
                    }
                }
                __builtin_amdgcn_s_setprio(1);
#pragma unroll
                for (int kf = 0; kf < 4; kf++) {
                    const bf16x8_t pa = *(const bf16x8_t*)&Pg[l31 * PG_S + kh * 64 + kf * 16 + hi * 8];
#pragma unroll
                    for (int dt = 0; dt < 2; dt++) {
                        const bf16x8_t vb = *(const bf16x8_t*)
                            &buf[(dh * 64 + dt * 32 + l31) * 64 + (((kf * 2 + hi) ^ (l31 & 7)) << 3)];
                        Op4[h * 2 + dt] =
                            __builtin_amdgcn_mfma_f32_32x32x16_bf16(pa, vb, Op4[h * 2 + dt], 0, 0, 0);
                    }
                }
                __builtin_amdgcn_s_setprio(0);
            }
        }
    }
#undef LOADSET

    // ---- finalize: reduce per-lane lrun, share via LDS, store Msg ----
#pragma unroll
    for (int r = 0; r < 4; r++) {
#pragma unroll
        for (int o = 1; o < 16; o <<= 1) lrun[r] += __shfl_xor(lrun[r], o);
    }
    if (fr == 0) {
#pragma unroll
        for (int r = 0; r < 4; r++) lrS[w * 16 + qd * 4 + r] = lrun[r];
    }
    __syncthreads();
    float inv16[16];
#pragma unroll
    for (int r = 0; r < 16; r++) {
        const int qrw = (r & 3) + 8 * (r >> 2) + 4 * hi;
        inv16[r] = 1.0f / lrS[qg * 32 + qrw];
    }
    float* outB = Msg + ((size_t)p * 3 + m) * BND_ + (size_t)batch * N_ * D_
                + (size_t)(qt * 64 + qg * 32) * D_;
#pragma unroll
    for (int i = 0; i < 4; i++) {
        const int dcol = (i >> 1) * 128 + dh * 64 + (i & 1) * 32 + l31;
#pragma unroll
        for (int r = 0; r < 16; r++) {
            const int qrw = (r & 3) + 8 * (r >> 2) + 4 * hi;
            outB[(size_t)qrw * D_ + dcol] = Op4[i][r] * inv16[r];
        }
    }
}

// ---------------------------------------------------------------------------
// Weight convert+transpose, all 5 weights in one dispatch (z selects).
// ---------------------------------------------------------------------------
__global__ __launch_bounds__(256) void wt_transpose_kernel(
    const float* __restrict__ W0, const float* __restrict__ W1,
    const float* __restrict__ W2, const float* __restrict__ W3,
    const float* __restrict__ W4, __hip_bfloat16* __restrict__ out)
{
    const int z = blockIdx.z;
    const float* in = z == 0 ? W0 : z == 1 ? W1 : z == 2 ? W2 : z == 3 ? W3 : W4;
    __hip_bfloat16* o = out + (size_t)z * D_ * D_;
    __shared__ float t[32][33];
    const int r0 = blockIdx.x * 32, c0 = blockIdx.y * 32;
    const int tx = threadIdx.x & 31, ty = threadIdx.x >> 5;
#pragma unroll
    for (int k = 0; k < 4; k++) {
        int r = ty + k * 8;
        t[r][tx] = in[(size_t)(r0 + r) * D_ + (c0 + tx)];
    }
    __syncthreads();
#pragma unroll
    for (int k = 0; k < 4; k++) {
        int r = ty + k * 8;
        o[(size_t)(c0 + r) * D_ + (r0 + tx)] = __float2bfloat16(t[tx][r]);
    }
}

// all 3 modality inputs fp32 -> bf16, one dispatch
__global__ void cvt3_kernel(const float* __restrict__ x0, const float* __restrict__ x1,
                            const float* __restrict__ x2, __hip_bfloat16* __restrict__ dst)
{
    const int z = blockIdx.z;
    const float* s = z == 0 ? x0 : z == 1 ? x1 : x2;
    const long long i = (long long)blockIdx.x * 256 + threadIdx.x;
    dst[(size_t)z * BND_ + i] = __float2bfloat16(s[i]);
}

// ---------------------------------------------------------------------------
// Fused hypergraph prep: per-modality block does count -> scan(N) -> scan(M)
// -> fill, all counters/offsets in LDS. Replaces zero/count/scan/scan/fill
// (5 serial launches -> 1).
// ---------------------------------------------------------------------------
__global__ __launch_bounds__(1024) void hg_prep_kernel(
    const int* __restrict__ i0, const int* __restrict__ i1, const int* __restrict__ i2,
    int* __restrict__ NOffs, int* __restrict__ EOffs,
    float* __restrict__ Dinv, float* __restrict__ Bnorm,
    int* __restrict__ NOrd, int* __restrict__ EOrd)
{
    const int z = blockIdx.z;
    const int* nidx = z == 0 ? i0 : z == 1 ? i1 : i2;
    const int* eidx = nidx + C_;
    NOffs += z * (N_ + 1); EOffs += z * (M_ + 1);
    Dinv += z * N_; Bnorm += z * M_;
    NOrd += z * C_; EOrd += z * C_;

    __shared__ int ncnt[N_];
    __shared__ int ecnt[M_];
    __shared__ int tmp[N_];
    __shared__ int noff[N_ + 1];
    __shared__ int eoff[M_ + 1];

    const int t = threadIdx.x;
    ncnt[t] = 0;
    if (t < M_) ecnt[t] = 0;
    __syncthreads();
#pragma unroll
    for (int c = t; c < C_; c += 1024) {
        atomicAdd(&ncnt[nidx[c]], 1);
        atomicAdd(&ecnt[eidx[c]], 1);
    }
    __syncthreads();
    // scan N (Hillis-Steele, inclusive)
    const int vn = ncnt[t];
    tmp[t] = vn;
    __syncthreads();
    for (int o = 1; o < N_; o <<= 1) {
        int x = (t >= o) ? tmp[t - o] : 0;
        __syncthreads();
        tmp[t] += x;
        __syncthreads();
    }
    noff[t] = tmp[t] - vn;
    NOffs[t] = tmp[t] - vn;
    if (t == N_ - 1) { noff[N_] = tmp[t]; NOffs[N_] = tmp[t]; }
    Dinv[t] = (vn > 0) ? (1.0f / (float)vn) : 0.0f;
    __syncthreads();
    // scan M
    int ve = 0;
    if (t < M_) { ve = ecnt[t]; tmp[t] = ve; }
    __syncthreads();
    for (int o = 1; o < M_; o <<= 1) {
        int x = (t >= o && t < M_) ? tmp[t - o] : 0;
        __syncthreads();
        if (t < M_) tmp[t] += x;
        __syncthreads();
    }
    if (t < M_) {
        eoff[t] = tmp[t] - ve;
        EOffs[t] = tmp[t] - ve;
        Bnorm[t] = (ve > 0) ? (1.0f / (float)ve) : 0.0f;
        if (t == M_ - 1) { eoff[M_] = tmp[t]; EOffs[M_] = tmp[t]; }
    }
    // reset counters, fill ordered lists
    ncnt[t] = 0;
    if (t < M_) ecnt[t] = 0;
    __syncthreads();
#pragma unroll
    for (int c = t; c < C_; c += 1024) {
        const int nd = nidx[c], ed = eidx[c];
        const int p1 = atomicAdd(&ncnt[nd], 1);
        NOrd[noff[nd] + p1] = c;
        const int p2 = atomicAdd(&ecnt[ed], 1);
        EOrd[eoff[ed] + p2] = c;
    }
}

// s1/s2 from bf16 xp; one wave per (md,b,n)
__global__ __launch_bounds__(64) void hg_s12_kernel(
    const unsigned short* __restrict__ Xp, const float* __restrict__ att,
    float* __restrict__ s1, float* __restrict__ s2)
{
    const int z = blockIdx.z;
    const int bid = blockIdx.x;
    const int b = bid >> 10;
    const int n = bid & (N_ - 1);
    const int lane = threadIdx.x;
    const unsigned short* xr = Xp + (size_t)z * BND_ + (size_t)(b * N_ + n) * D_;
    const ushort4 u = ((const ushort4*)xr)[lane];
    const float4 a1 = ((const float4*)att)[lane];
    const float4 a2 = ((const float4*)(att + D_))[lane];
    float d1 = bf2f(u.x) * a1.x + bf2f(u.y) * a1.y + bf2f(u.z) * a1.z + bf2f(u.w) * a1.w;
    float d2 = bf2f(u.x) * a2.x + bf2f(u.y) * a2.y + bf2f(u.z) * a2.z + bf2f(u.w) * a2.w;
#pragma unroll
    for (int o = 32; o > 0; o >>= 1) { d1 += __shfl_down(d1, o); d2 += __shfl_down(d2, o); }
    if (lane == 0) { s1[z * NB_ + n * 16 + b] = d1; s2[z * NB_ + n * 16 + b] = d2; }
}

// edge_s2[m,b]: atomic-free, grid (M_,1,3), 16 pos x 16 b LDS reduce.
__global__ __launch_bounds__(256) void hg_edge_s2_kernel(
    const int* __restrict__ i0, const int* __restrict__ i1, const int* __restrict__ i2,
    const int* __restrict__ eoffs, const int* __restrict__ eord,
    const float* __restrict__ s2, float* __restrict__ edge_s2)
{
    const int z = blockIdx.z;
    const int* nidx = z == 0 ? i0 : z == 1 ? i1 : i2;
    eoffs += z * (M_ + 1); eord += z * C_;
    s2 += z * NB_; edge_s2 += (size_t)z * M_ * 16;

    const int m = blockIdx.x;
    const int pos = threadIdx.x >> 4;
    const int b = threadIdx.x & 15;
    const int base = eoffs[m];
    const int len = eoffs[m + 1] - base;
    float acc = 0.0f;
#pragma unroll 4
    for (int i = pos; i < len; i += 16) {
        int c = eord[base + i];
        acc += s2[nidx[c] * 16 + b];
    }
    __shared__ float red[16][16];
    red[pos][b] = acc;
    __syncthreads();
    for (int s = 8; s > 0; s >>= 1) {
        if (pos < s) red[pos][b] += red[pos + s][b];
        __syncthreads();
    }
    if (pos == 0) edge_s2[m * 16 + b] = red[0][b];
}

__global__ __launch_bounds__(256) void hg_node_softmax_kernel(
    const int* __restrict__ i0, const int* __restrict__ i1, const int* __restrict__ i2,
    const int* __restrict__ noffs, const int* __restrict__ nord,
    const float* __restrict__ s1, const float* __restrict__ edge_s2,
    float* __restrict__ ee, float* __restrict__ inv_sum)
{
    const int z = blockIdx.z;
    const int* eidx = (z == 0 ? i0 : z == 1 ? i1 : i2) + C_;
    noffs += z * (N_ + 1); nord += z * C_;
    s1 += z * NB_; edge_s2 += (size_t)z * M_ * 16;
    ee += (size_t)z * C_ * 16; inv_sum += z * NB_;

    const int n = blockIdx.x;
    const int base = noffs[n];
    const int len = noffs[n + 1] - base;
    if (len == 0) return;
    const int cp = threadIdx.x >> 4;
    const int b = threadIdx.x & 15;
    __shared__ float red[16][16];
    const float s1nb = s1[n * 16 + b];

    float mx = -1e30f;
    for (int i = cp; i < len; i += 16) {
        int c = nord[base + i];
        float e = s1nb + edge_s2[eidx[c] * 16 + b];
        e = e > 0.0f ? e : 0.2f * e;      // leaky_relu 0.2
        mx = fmaxf(mx, e);
    }
    red[cp][b] = mx;
    __syncthreads();
    for (int s = 8; s > 0; s >>= 1) {
        if (cp < s) red[cp][b] = fmaxf(red[cp][b], red[cp + s][b]);
        __syncthreads();
    }
    mx = red[0][b];
    __syncthreads();

    float sm = 0.0f;
    for (int i = cp; i < len; i += 16) {
        int c = nord[base + i];
        float e = s1nb + edge_s2[eidx[c] * 16 + b];
        e = e > 0.0f ? e : 0.2f * e;
        float ex = __expf(e - mx);
        ee[c * 16 + b] = ex;
        sm += ex;
    }
    red[cp][b] = sm;
    __syncthreads();
    for (int s = 8; s > 0; s >>= 1) {
        if (cp < s) red[cp][b] += red[cp + s][b];
        __syncthreads();
    }
    if (cp == 0) inv_sum[n * 16 + b] = 1.0f / (red[0][b] + 1e-16f);
}

// Pack sorted-order gather arrays (kills dependent chains in xedge/xnode).
__global__ __launch_bounds__(256) void hg_pack_kernel(
    const int* __restrict__ i0, const int* __restrict__ i1, const int* __restrict__ i2,
    const int* __restrict__ nord, const int* __restrict__ eord,
    const float* __restrict__ ee, const float* __restrict__ inv_sum,
    int* __restrict__ EmS, int* __restrict__ NnS,
    float* __restrict__ CoefN, float* __restrict__ CoefE)
{
    const int z = blockIdx.z;
    const int* nidx = z == 0 ? i0 : z == 1 ? i1 : i2;
    const int* eidx = nidx + C_;
    nord += z * C_; eord += z * C_;
    ee += (size_t)z * C_ * 16; inv_sum += z * NB_;
    EmS += z * C_; NnS += z * C_;
    CoefN += (size_t)z * C_ * 16; CoefE += (size_t)z * C_ * 16;

    const int gid = blockIdx.x * 256 + threadIdx.x;   // C*16
    const int i = gid >> 4, b = gid & 15;
    const int c1 = nord[i], c2 = eord[i];
    const int n1 = nidx[c1], n2 = nidx[c2];
    if (b == 0) { EmS[i] = eidx[c1]; NnS[i] = n2; }
    CoefN[i * 16 + b] = ee[c1 * 16 + b] * inv_sum[n1 * 16 + b];
    CoefE[i * 16 + b] = ee[c2 * 16 + b] * inv_sum[n2 * 16 + b];
}

// x_edge[m,b,:] via packed arrays.
__global__ __launch_bounds__(256) void hg_xedge_kernel(
    const int* __restrict__ eoffs, const int* __restrict__ NnS,
    const float* __restrict__ CoefE, const unsigned short* __restrict__ Xp,
    const float* __restrict__ Bnorm, float* __restrict__ x_edge)
{
    const int z = blockIdx.z;
    eoffs += z * (M_ + 1); NnS += z * C_;
    CoefE += (size_t)z * C_ * 16;
    const unsigned short* xp = Xp + (size_t)z * BND_;
    Bnorm += z * M_; x_edge += (size_t)z * M_ * B_ * D_;

    const int m = blockIdx.x >> 4;
    const int b = blockIdx.x & 15;
    const int d = threadIdx.x;
    const int base = eoffs[m];
    const int len = eoffs[m + 1] - base;
    float acc = 0.0f;
#pragma unroll 4
    for (int i = 0; i < len; i++) {
        const int nn = NnS[base + i];
        const float cf = CoefE[(size_t)(base + i) * 16 + b];
        acc += cf * bf2f(xp[(size_t)(b * N_ + nn) * D_ + d]);
    }
    x_edge[((size_t)(m * 16 + b)) * D_ + d] = Bnorm[m] * acc;
}

// h[b,n,:] via packed arrays.
__global__ __launch_bounds__(256) void hg_xnode_kernel(
    const int* __restrict__ noffs, const int* __restrict__ EmS,
    const float* __restrict__ CoefN, const float* __restrict__ x_edge,
    const float* __restrict__ Dinv, __hip_bfloat16* __restrict__ Hbf)
{
    const int z = blockIdx.z;
    noffs += z * (N_ + 1); EmS += z * C_;
    CoefN += (size_t)z * C_ * 16;
    x_edge += (size_t)z * M_ * B_ * D_; Dinv += z * N_;
    __hip_bfloat16* hbf = Hbf + (size_t)z * BND_;

    const int n = blockIdx.x >> 4;
    const int b = blockIdx.x & 15;
    const int d = threadIdx.x;
    const int base = noffs[n];
    const int len = noffs[n + 1] - base;
    float acc = 0.0f;
#pragma unroll 4
    for (int i = 0; i < len; i++) {
        const int em = EmS[base + i];
        const float cf = CoefN[(size_t)(base + i) * 16 + b];
        acc += cf * x_edge[((size_t)(em * 16 + b)) * D_ + d];
    }
    hbf[((size_t)(b * N_ + n)) * D_ + d] = __float2bfloat16(Dinv[n] * acc);
}

// ---------------------------------------------------------------------------
// Host
// ---------------------------------------------------------------------------
static inline void launch_gemm(hipStream_t s, dim3 grid,
                               const void* A0, const void* A1, int lda, long long sA,
                               const void* B0, const void* B1, int ldb, long long sB,
                               void* Cv, int ldc, long long sC, long long cOff, long long pieceCs,
                               int K, int kPiece, int zBatches,
                               float scale, const float* bias,
                               const float* a0, const float* a1, int epi)
{
    gemm_nt_kernel<<<grid, 256, 0, s>>>((const __hip_bfloat16*)A0, (const __hip_bfloat16*)A1,
                                        lda, sA,
                                        (const __hip_bfloat16*)B0, (const __hip_bfloat16*)B1,
                                        ldb, sB,
                                        Cv, ldc, sC, cOff, pieceCs, K, kPiece, zBatches,
                                        scale, bias, a0, a1, epi);
}

extern "C" void kernel_launch(void* const* d_in, const int* in_sizes, int n_in,
                              void* d_out, int out_size, void* d_ws, size_t ws_size,
                              hipStream_t stream)
{
    (void)in_sizes; (void)n_in; (void)out_size; (void)ws_size;

    const float* x0 = (const float*)d_in[0];
    const float* x1 = (const float*)d_in[1];
    const float* x2 = (const float*)d_in[2];
    const int* h0 = (const int*)d_in[3];
    const int* h1 = (const int*)d_in[4];
    const int* h2 = (const int*)d_in[5];
    const float* W_hg  = (const float*)d_in[6];
    const float* att_hg= (const float*)d_in[7];
    const float* WQ = (const float*)d_in[8];
    const float* bQ = (const float*)d_in[9];
    const float* WK = (const float*)d_in[10];
    const float* bK = (const float*)d_in[11];
    const float* WV = (const float*)d_in[12];
    const float* bV = (const float*)d_in[13];
    const float* WO = (const float*)d_in[14];
    const float* bO = (const float*)d_in[15];
    float* outp = (float*)d_out;

    char* ws = (char*)d_ws;
    size_t off = 0;
    auto take = [&](size_t bytes) { size_t r = off; off += (bytes + 255) & ~(size_t)255; return r; };

    const size_t oWt   = take((size_t)5 * D_ * D_ * 2);          // 0.63 MB
    const size_t oHbf  = take((size_t)3 * BND_ * 2);             // 24 MB
    const size_t oKall = take((size_t)3 * BND_ * 2);             // 24 MB
    const size_t oVt   = take((size_t)3 * BND_ * 2);             // 24 MB
    const size_t oQall = take((size_t)3 * BND_ * 2);             // 24 MB
    const size_t oBIG  = take((size_t)6 * BND_ * 4);             // 96 MB: Xc+Xp | Msg(2)
    const size_t oXe   = take((size_t)3 * M_ * B_ * D_ * 4);     // 6 MB
    const size_t oEE   = take((size_t)3 * C_ * 16 * 4);
    const size_t oCoefN= take((size_t)3 * C_ * 16 * 4);
    const size_t oCoefE= take((size_t)3 * C_ * 16 * 4);
    const size_t oEmS  = take((size_t)3 * C_ * 4);
    const size_t oNnS  = take((size_t)3 * C_ * 4);
    const size_t oS1   = take((size_t)3 * NB_ * 4);
    const size_t oS2   = take((size_t)3 * NB_ * 4);
    const size_t oInv  = take((size_t)3 * NB_ * 4);
    const size_t oEs2  = take((size_t)3 * M_ * 16 * 4);
    const size_t oNOffs= take((size_t)3 * (N_ + 1) * 4);
    const size_t oEOffs= take((size_t)3 * (M_ + 1) * 4);
    const size_t oNOrd = take((size_t)3 * C_ * 4);
    const size_t oEOrd = take((size_t)3 * C_ * 4);
    const size_t oDinv = take((size_t)3 * N_ * 4);
    const size_t oBnorm= take((size_t)3 * M_ * 4);

    __hip_bfloat16* Wt   = (__hip_bfloat16*)(ws + oWt);
    __hip_bfloat16* Hbf  = (__hip_bfloat16*)(ws + oHbf);
    __hip_bfloat16* Kall = (__hip_bfloat16*)(ws + oKall);
    __hip_bfloat16* Vt   = (__hip_bfloat16*)(ws + oVt);
    __hip_bfloat16* Qall = (__hip_bfloat16*)(ws + oQall);
    __hip_bfloat16* Xc   = (__hip_bfloat16*)(ws + oBIG);
    __hip_bfloat16* Xp   = (__hip_bfloat16*)(ws + oBIG + (size_t)3 * BND_ * 2);
    float* Msg  = (float*)(ws + oBIG);
    float* Xe   = (float*)(ws + oXe);
    float* EE   = (float*)(ws + oEE);
    float* CoefN= (float*)(ws + oCoefN);
    float* CoefE= (float*)(ws + oCoefE);
    int*   EmS  = (int*)(ws + oEmS);
    int*   NnS  = (int*)(ws + oNnS);
    float* S1f  = (float*)(ws + oS1);
    float* S2f  = (float*)(ws + oS2);
    float* Inv  = (float*)(ws + oInv);
    float* Es2  = (float*)(ws + oEs2);
    int*   NOffs = (int*)(ws + oNOffs);
    int*   EOffs = (int*)(ws + oEOffs);
    int*   NOrd  = (int*)(ws + oNOrd);
    int*   EOrd  = (int*)(ws + oEOrd);
    float* Dinv  = (float*)(ws + oDinv);
    float* Bnorm = (float*)(ws + oBnorm);

    const int WN = D_ * D_;
    __hip_bfloat16* WtHG = Wt;
    __hip_bfloat16* WtO  = Wt + (size_t)4 * WN;

    // -------- Phase 0: weights (one dispatch) -------------------------------
    wt_transpose_kernel<<<dim3(8, 8, 5), 256, 0, stream>>>(W_hg, WQ, WK, WV, WO, Wt);

    // -------- Phase 1: hypergraph conv, all modalities batched --------------
    cvt3_kernel<<<dim3((unsigned)(BND_ / 256), 1, 3), 256, 0, stream>>>(x0, x1, x2, Xc);
    hg_prep_kernel<<<dim3(1, 1, 3), 1024, 0, stream>>>(h0, h1, h2, NOffs, EOffs,
                                                       Dinv, Bnorm, NOrd, EOrd);
    launch_gemm(stream, dim3(BN_ / 128, D_ / 128, 3),
                Xc, Xc, D_, BND_, WtHG, WtHG, D_, 0,
                Xp, D_, BND_, 0, 0, D_, D_, 3,
                1.0f, nullptr, nullptr, nullptr, 1);
    hg_s12_kernel<<<dim3(BN_, 1, 3), 64, 0, stream>>>((const unsigned short*)Xp, att_hg, S1f, S2f);
    hg_edge_s2_kernel<<<dim3(M_, 1, 3), 256, 0, stream>>>(h0, h1, h2, EOffs, EOrd, S2f, Es2);
    hg_node_softmax_kernel<<<dim3(N_, 1, 3), 256, 0, stream>>>(h0, h1, h2, NOffs, NOrd,
                                                               S1f, Es2, EE, Inv);
    hg_pack_kernel<<<dim3(C_ * 16 / 256, 1, 3), 256, 0, stream>>>(h0, h1, h2, NOrd, EOrd,
                                                                  EE, Inv, EmS, NnS, CoefN, CoefE);
    hg_xedge_kernel<<<dim3(M_ * B_, 1, 3), 256, 0, stream>>>(EOffs, NnS, CoefE,
                                                             (const unsigned short*)Xp, Bnorm, Xe);
    hg_xnode_kernel<<<dim3(N_ * B_, 1, 3), 256, 0, stream>>>(NOffs, EmS, CoefN, Xe, Dinv, Hbf);

    // -------- Phase 2: K, V, Q fused in one dispatch ------------------------
    qkv_gemm_kernel<<<dim3(3 * BN_ / 128, D_ / 128, 3), 256, 0, stream>>>(
        Hbf, Wt, bQ, bK, bV, Qall, Kall, Vt);

    // -------- Phase 3: fused flash attention + output -----------------------
    flash_attn_kernel<<<dim3(1536, 1, 1), 256, 0, stream>>>(Qall, Kall, Vt, Msg);
    launch_gemm(stream, dim3(BN_ / 128, D_ / 128, 3),
                Hbf, Hbf, D_, BND_, WtO, WtO, D_, 0,
                outp, D_, BND_, 0, 0, D_, D_, 3,
                1.0f, bO, Msg, Msg + (size_t)3 * BND_, 2);
}

// Round 10
// 604.106 us; speedup vs baseline: 1.1638x; 1.0258x over previous
//
#include <hip/hip_runtime.h>
#include <hip/hip_bf16.h>
#include <stdint.h>

// ---------------------------------------------------------------------------
// B=16, N=1024, D=256, M=128, C=8192. fp32 in/out, bf16 MFMA internally.
// Output: 3 x [B,N,D] fp32 concatenated.
// Attention fully fused (flash-style). NOTE: all register-array indices in the
// flash kernel MUST be compile-time (runtime index -> scratch spill, R10: 2.3GB
// of spill writes, 7x regression).
// R1: flash 64-wide chunks, 8 phases/kt, partner split on grid.
// R2: 2-phase-deep register prefetch + s_setprio around MFMA clusters.
// R3: XCD-aware 1-D grid swizzle (FETCH 418->74MB).
// R4: __launch_bounds__(256,2) -> 2 waves/SIMD; T13 defer-max.
// R5: PV -> mfma_32x32x16 via wave-pair shared P; shuffle-free softmax.
// R6 (REVERTED): direct-global K gather (512B stride = 16 lines/instr, 2.3x).
// R7: FA_S->64 + XOR chunk swizzle; conflicts 12.6M->6.3M. Flash ~91%
//     LDS-pipe-busy - near its structural floor.
// R8: hg_prep fusion + epi=5 transposed V store (KEPT). PG_S 132 reverted
//     (264B not 16B-aligned -> split ds_reads).
// R9: PG_S=136; K/V/Q fused into one qkv_gemm dispatch. 619.7us.
// R10: Msg interface fp32 -> bf16: flash writes bf16 Msg (2x24MB instead of
//     2x48MB), final gemm epi=2 reads bf16 adds. Saves ~96MB HBM round-trip;
//     error budget: Msg is an O(1) additive term, bf16 adds <=0.4% rel.
// ---------------------------------------------------------------------------

namespace {
constexpr int B_ = 16;
constexpr int N_ = 1024;
constexpr int D_ = 256;
constexpr int M_ = 128;
constexpr int C_ = 8192;
constexpr int BN_ = B_ * N_;                       // 16384
constexpr long long BND_ = (long long)BN_ * D_;    // 4,194,304 elems
constexpr int NB_ = N_ * B_;                       // 16384
constexpr int LDA_S = 40;                          // K-loop LDS stride (shorts)
constexpr int EPI_S = 68;                          // epilogue LDS stride (floats)
constexpr int PG_S = 136;                          // flash P stride: 272B, 16B-aligned
}

typedef short bf16x8_t __attribute__((ext_vector_type(8)));
typedef float f32x4_t __attribute__((ext_vector_type(4)));
typedef float f32x16_t __attribute__((ext_vector_type(16)));
typedef unsigned short u16x8_t __attribute__((ext_vector_type(8)));

#define DEV static __device__ __forceinline__
DEV float bf2f(unsigned short u) { return __uint_as_float((unsigned)u << 16); }
DEV unsigned short f2bf_bits(float x) { return __builtin_bit_cast(unsigned short, __float2bfloat16(x)); }

// ---------------------------------------------------------------------------
// NT bf16 MFMA GEMM, 128x128 tile, BK=32, 4 waves, LDS-transposed epilogue.
// epi: 0 = fp32 C = v (v = acc*scale)
//      1 = bf16 C = v + bias[col]
//      2 = fp32 C = relu(v + bias[col] + bf16(add0[idx]) + bf16(add1[idx]))
//      4 = bf16 C = v + bias[col]*scale      (i.e. (acc+bias)*scale)
// ---------------------------------------------------------------------------
__global__ __launch_bounds__(256) void gemm_nt_kernel(
    const __hip_bfloat16* __restrict__ A0, const __hip_bfloat16* __restrict__ A1,
    int lda, long long sA,
    const __hip_bfloat16* __restrict__ B0, const __hip_bfloat16* __restrict__ B1,
    int ldb, long long sB,
    void* __restrict__ Cv, int ldc, long long sC, long long cOff, long long pieceCs,
    int K, int kPiece, int zBatches,
    float scale, const float* __restrict__ bias,
    const void* __restrict__ add0, const void* __restrict__ add1,
    int epi)
{
    __shared__ __align__(16) char smem[20480];
    short* smA = (short*)smem;
    short* smB = (short*)(smem + 10240);

    const int tid = threadIdx.x;
    const int wid = tid >> 6;
    const int lane = tid & 63;
    const int z = blockIdx.z;
    const int batch = z % zBatches;
    const int rem = z / zBatches;
    const int pi = rem & 1;
    const int kh = rem >> 1;

    const short* Ab = (const short*)(pi ? A1 : A0) + (size_t)batch * sA
                    + (size_t)blockIdx.x * 128 * lda + (size_t)kh * kPiece;
    const short* Bb = (const short*)(pi ? B1 : B0) + (size_t)batch * sB
                    + (size_t)blockIdx.y * 128 * ldb + (size_t)kh * kPiece;

    const int wm = (wid >> 1) * 64;
    const int wn = (wid & 1) * 64;
    const int fr = lane & 15;
    const int kq = (lane >> 4) * 8;
    const int sr = tid >> 2;
    const int sc = (tid & 3) * 8;

    f32x4_t acc[4][4] = {};
    int4 avv[2], bvv[2];
#pragma unroll
    for (int h = 0; h < 2; h++) {
        const int row = h * 64 + sr;
        avv[h] = *(const int4*)(Ab + (size_t)row * lda + sc);
        bvv[h] = *(const int4*)(Bb + (size_t)row * ldb + sc);
    }

    for (int k0 = 0; k0 < K; k0 += 32) {
        __syncthreads();
#pragma unroll
        for (int h = 0; h < 2; h++) {
            const int row = h * 64 + sr;
            *(int4*)&smA[row * LDA_S + sc] = avv[h];
            *(int4*)&smB[row * LDA_S + sc] = bvv[h];
        }
        __syncthreads();

        const int kn = k0 + 32;
        if (kn < K) {
#pragma unroll
            for (int h = 0; h < 2; h++) {
                const int row = h * 64 + sr;
                avv[h] = *(const int4*)(Ab + (size_t)row * lda + (kn + sc));
                bvv[h] = *(const int4*)(Bb + (size_t)row * ldb + (kn + sc));
            }
        }

        bf16x8_t af[4], bfv[4];
#pragma unroll
        for (int i = 0; i < 4; i++)
            af[i] = *(const bf16x8_t*)&smA[(wm + i * 16 + fr) * LDA_S + kq];
#pragma unroll
        for (int j = 0; j < 4; j++)
            bfv[j] = *(const bf16x8_t*)&smB[(wn + j * 16 + fr) * LDA_S + kq];
#pragma unroll
        for (int i = 0; i < 4; i++)
#pragma unroll
            for (int j = 0; j < 4; j++)
                acc[i][j] = __builtin_amdgcn_mfma_f32_16x16x32_bf16(af[i], bfv[j], acc[i][j], 0, 0, 0);
    }

    const int r_ = lane >> 4;
    float* lts = (float*)smem + wid * (16 * EPI_S);
#pragma unroll
    for (int i = 0; i < 4; i++) {
        __syncthreads();
#pragma unroll
        for (int j = 0; j < 4; j++)
#pragma unroll
            for (int r = 0; r < 4; r++)
                lts[(r_ * 4 + r) * EPI_S + j * 16 + fr] = acc[i][j][r] * scale;
        __syncthreads();
#pragma unroll
        for (int t = 0; t < 4; t++) {
            const int lrow = t * 4 + r_;
            const f32x4_t v4 = *(const f32x4_t*)&lts[lrow * EPI_S + fr * 4];
            const int row = blockIdx.x * 128 + wm + i * 16 + lrow;
            const int col = blockIdx.y * 128 + wn + fr * 4;
            const size_t idx = (size_t)batch * sC + (size_t)row * ldc + col;
            const size_t gidx = (size_t)cOff + (size_t)rem * pieceCs + idx;
            if (epi == 0) {
                *(f32x4_t*)((float*)Cv + gidx) = v4;
            } else if (epi == 1 || epi == 4) {
                f32x4_t bb = {0.f, 0.f, 0.f, 0.f};
                if (bias) bb = *(const f32x4_t*)(bias + col);
                const float bs = (epi == 4) ? scale : 1.0f;
                ushort4 pk;
                pk.x = f2bf_bits(v4[0] + bb[0] * bs);
                pk.y = f2bf_bits(v4[1] + bb[1] * bs);
                pk.z = f2bf_bits(v4[2] + bb[2] * bs);
                pk.w = f2bf_bits(v4[3] + bb[3] * bs);
                *(ushort4*)((unsigned short*)Cv + gidx) = pk;
            } else {
                const f32x4_t bb = *(const f32x4_t*)(bias + col);
                const ushort4 m0u = *(const ushort4*)((const unsigned short*)add0 + idx);
                const ushort4 m1u = *(const ushort4*)((const unsigned short*)add1 + idx);
                f32x4_t o;
                o[0] = v4[0] + bb[0] + bf2f(m0u.x) + bf2f(m1u.x);
                o[1] = v4[1] + bb[1] + bf2f(m0u.y) + bf2f(m1u.y);
                o[2] = v4[2] + bb[2] + bf2f(m0u.z) + bf2f(m1u.z);
                o[3] = v4[3] + bb[3] + bf2f(m0u.w) + bf2f(m1u.w);
#pragma unroll
                for (int k = 0; k < 4; k++) o[k] = o[k] > 0.0f ? o[k] : 0.0f;
                *(f32x4_t*)((float*)Cv + gidx) = o;
            }
        }
    }
}

// ---------------------------------------------------------------------------
// Fused K/V/Q projection: one dispatch, grid (3*BN/128, D/128, 3).
// z=0: Kall = bf16(H @ WtK + bK)
// z=1: Vt   = transposed bf16 store (epi5 pattern): Vt[mb][d][n]
// z=2: Qall = bf16((H @ WtQ + bQ) * 1/16)
// ---------------------------------------------------------------------------
__global__ __launch_bounds__(256) void qkv_gemm_kernel(
    const __hip_bfloat16* __restrict__ Hbf, const __hip_bfloat16* __restrict__ Wt,
    const float* __restrict__ bQ, const float* __restrict__ bK, const float* __restrict__ bV,
    __hip_bfloat16* __restrict__ Qall, __hip_bfloat16* __restrict__ Kall,
    __hip_bfloat16* __restrict__ Vt)
{
    __shared__ __align__(16) char smem[20480];
    short* smA = (short*)smem;
    short* smB = (short*)(smem + 10240);

    const int tid = threadIdx.x;
    const int wid = tid >> 6;
    const int lane = tid & 63;
    const int z = blockIdx.z;                     // 0=K 1=V 2=Q
    const int WN = D_ * D_;
    // Wt layout: [W_hg, WQ, WK, WV, WO]
    const short* Bb = (const short*)Wt + (size_t)(z == 0 ? 2 : z == 1 ? 3 : 1) * WN
                    + (size_t)blockIdx.y * 128 * D_;
    const float* bias = z == 0 ? bK : z == 1 ? bV : bQ;
    const short* Ab = (const short*)Hbf + (size_t)blockIdx.x * 128 * D_;

    const int wm = (wid >> 1) * 64;
    const int wn = (wid & 1) * 64;
    const int fr = lane & 15;
    const int kq = (lane >> 4) * 8;
    const int sr = tid >> 2;
    const int sc = (tid & 3) * 8;

    f32x4_t acc[4][4] = {};
    int4 avv[2], bvv[2];
#pragma unroll
    for (int h = 0; h < 2; h++) {
        const int row = h * 64 + sr;
        avv[h] = *(const int4*)(Ab + (size_t)row * D_ + sc);
        bvv[h] = *(const int4*)(Bb + (size_t)row * D_ + sc);
    }

    for (int k0 = 0; k0 < D_; k0 += 32) {
        __syncthreads();
#pragma unroll
        for (int h = 0; h < 2; h++) {
            const int row = h * 64 + sr;
            *(int4*)&smA[row * LDA_S + sc] = avv[h];
            *(int4*)&smB[row * LDA_S + sc] = bvv[h];
        }
        __syncthreads();

        const int kn = k0 + 32;
        if (kn < D_) {
#pragma unroll
            for (int h = 0; h < 2; h++) {
                const int row = h * 64 + sr;
                avv[h] = *(const int4*)(Ab + (size_t)row * D_ + (kn + sc));
                bvv[h] = *(const int4*)(Bb + (size_t)row * D_ + (kn + sc));
            }
        }

        bf16x8_t af[4], bfv[4];
#pragma unroll
        for (int i = 0; i < 4; i++)
            af[i] = *(const bf16x8_t*)&smA[(wm + i * 16 + fr) * LDA_S + kq];
#pragma unroll
        for (int j = 0; j < 4; j++)
            bfv[j] = *(const bf16x8_t*)&smB[(wn + j * 16 + fr) * LDA_S + kq];
#pragma unroll
        for (int i = 0; i < 4; i++)
#pragma unroll
            for (int j = 0; j < 4; j++)
                acc[i][j] = __builtin_amdgcn_mfma_f32_16x16x32_bf16(af[i], bfv[j], acc[i][j], 0, 0, 0);
    }

    const int r_ = lane >> 4;

    if (z == 1) {
        // transposed store into Vt: lane col = fr (fixed), 4 consecutive rows.
#pragma unroll
        for (int i = 0; i < 4; i++) {
            const int row = blockIdx.x * 128 + wm + i * 16 + r_ * 4;
            const int mb = row >> 10;
            const int nl = row & 1023;
#pragma unroll
            for (int j = 0; j < 4; j++) {
                const int col = blockIdx.y * 128 + wn + j * 16 + fr;
                const float bb = bias[col];
                ushort4 pk;
                pk.x = f2bf_bits(acc[i][j][0] + bb);
                pk.y = f2bf_bits(acc[i][j][1] + bb);
                pk.z = f2bf_bits(acc[i][j][2] + bb);
                pk.w = f2bf_bits(acc[i][j][3] + bb);
                *(ushort4*)((unsigned short*)Vt + ((size_t)mb * D_ + col) * 1024 + nl) = pk;
            }
        }
        return;
    }

    const float oscale = (z == 2) ? 0.0625f : 1.0f;
    unsigned short* Cv = (unsigned short*)(z == 0 ? Kall : Qall);
    float* lts = (float*)smem + wid * (16 * EPI_S);
#pragma unroll
    for (int i = 0; i < 4; i++) {
        __syncthreads();
#pragma unroll
        for (int j = 0; j < 4; j++)
#pragma unroll
            for (int r = 0; r < 4; r++)
                lts[(r_ * 4 + r) * EPI_S + j * 16 + fr] = acc[i][j][r];
        __syncthreads();
#pragma unroll
        for (int t = 0; t < 4; t++) {
            const int lrow = t * 4 + r_;
            const f32x4_t v4 = *(const f32x4_t*)&lts[lrow * EPI_S + fr * 4];
            const int row = blockIdx.x * 128 + wm + i * 16 + lrow;
            const int col = blockIdx.y * 128 + wn + fr * 4;
            const f32x4_t bb = *(const f32x4_t*)(bias + col);
            ushort4 pk;
            pk.x = f2bf_bits((v4[0] + bb[0]) * oscale);
            pk.y = f2bf_bits((v4[1] + bb[1]) * oscale);
            pk.z = f2bf_bits((v4[2] + bb[2]) * oscale);
            pk.w = f2bf_bits((v4[3] + bb[3]) * oscale);
            *(ushort4*)(Cv + (size_t)row * D_ + col) = pk;
        }
    }
}

// ---------------------------------------------------------------------------
// Fused flash attention. 1-D grid of 1536 slots, XCD-swizzled (R3).
// Block = 64 Q-rows of one (m,batch,partner). Per kv-tile kt: 8 phases of
// 128x64 bf16 chunks (4 K d-chunks, then 4 V chunks) into 2x16KB ping-pong;
// ONE barrier per phase, 2-deep register prefetch.
// LDS layout: linear [128][64] shorts with XOR chunk swizzle c' = c ^ (row&7)
// on write and both reads. Pg stride PG_S=136 (272B, 16B-aligned; do NOT use
// non-multiple-of-8 strides: 132 broke ds_read_b128 -> split reads, R8).
// QK^T: 16x16x32, wave w owns q-rows w*16+[0,16).
// PV:   32x32x16, wave-pair shares P; wave (qg,dh) owns 32q x {dh*64 cols}.
// Softmax: per-lane partial max + __all trigger; lrun per-lane, reduced at
// epilogue; defer-max rescale at vp==0 via LDS alpha array.
// Msg[p][m][b][n][d] BF16 (R10) = softmax(Q_m K_p^T /16) @ V_p
// ---------------------------------------------------------------------------
__global__ __launch_bounds__(256, 2) void flash_attn_kernel(
    const __hip_bfloat16* __restrict__ Qall,   // [3][16][1024][256] bf16, pre-scaled by 1/16
    const __hip_bfloat16* __restrict__ Kall,   // [3][16][1024][256] bf16
    const __hip_bfloat16* __restrict__ Vt,     // [3][16][256][1024] bf16
    __hip_bfloat16* __restrict__ Msg)          // [2][3][16][1024][256] bf16
{
    __shared__ __align__(16) short smKV[2][128 * 64];    // 2 x 16384 B ping-pong
    __shared__ __align__(16) short smP2[2][32 * PG_S];   // wave-pair shared P
    __shared__ float lrS[64];
    __shared__ float alS[64];
    __shared__ int   flS[4];

    const int tid = threadIdx.x;
    const int w = tid >> 6;
    const int lane = tid & 63;
    const int fr = lane & 15;
    const int qd = lane >> 4;
    const int l31 = lane & 31;
    const int hi = lane >> 5;
    const int qg = w >> 1;           // PV q-group (rows qg*32 + [0,32))
    const int dh = w & 1;            // PV d-subcolumn selector

    // XCD-aware decode: slot -> (qt, batch, zz). Bijective on [0,1536).
    const int slot = blockIdx.x;
    const int xcd = slot & 7;
    const int t_ = slot >> 3;
    const int qt = t_ & 15;
    const int gh = t_ >> 4;          // g/8, 0..11
    const int g = gh * 8 + xcd;      // group = batch + 16*zz, 0..95
    const int batch = g & 15;
    const int zz = g >> 4;           // 0..5
    const int m = zz >> 1;
    const int p = zz & 1;
    const int pn = (p == 0) ? (m == 0 ? 1 : 0) : (m == 2 ? 1 : 2);

    short* Pg = smP2[qg];            // [32][PG_S]

    // Q fragments: A[m=fr][k=qd*8+j] for 8 d-chunks, wave rows qt*64+w*16+fr
    const size_t qrow = ((size_t)(m * 16 + batch) * 1024) + qt * 64 + w * 16 + fr;
    const short* qp = (const short*)Qall + qrow * 256 + qd * 8;
    bf16x8_t qa[8];
#pragma unroll
    for (int c = 0; c < 8; c++) qa[c] = *(const bf16x8_t*)(qp + c * 32);

    const short* Kb = (const short*)Kall + ((size_t)(pn * 16 + batch) * 1024) * 256;
    const short* Vb = (const short*)Vt + ((size_t)(pn * 16 + batch) * 256) * 1024;

    const int row0 = tid >> 2;            // staging row 0..63 (plus +64)
    const int row1 = row0 + 64;
    const int colb = (tid & 3) * 16;      // global staging short-col (2 int4/row)
    // swizzled LDS chunk offsets (shorts) for this lane's two 16B chunks
    const int swkey = (tid >> 2) & 7;
    const int cA8 = (((tid & 3) * 2) ^ swkey) * 8;
    const int cB8 = (((tid & 3) * 2 + 1) ^ swkey) * 8;

    f32x16_t Op4[4] = {};                 // O[32q x 32d] tiles: i = h*2+dt
    float mrun[4] = {-1e30f, -1e30f, -1e30f, -1e30f};
    float lrun[4] = {0.f, 0.f, 0.f, 0.f}; // PER-LANE partial sums

#define LOADSET(p0, p1, p2, p3, base, stride)                                  \
    do {                                                                       \
        const short* _b = (base);                                              \
        p0 = *(const int4*)(_b + (size_t)row0 * (stride));                     \
        p1 = *(const int4*)(_b + (size_t)row0 * (stride) + 8);                 \
        p2 = *(const int4*)(_b + (size_t)row1 * (stride));                     \
        p3 = *(const int4*)(_b + (size_t)row1 * (stride) + 8);                 \
    } while (0)

    // prologue: phase 0 (K dc=0) into stE, phase 1 (K dc=1) into stO
    int4 e0, e1, e2, e3, o0, o1, o2, o3;
    LOADSET(e0, e1, e2, e3, Kb + colb, 256);
    LOADSET(o0, o1, o2, o3, Kb + 64 + colb, 256);

    for (int kt = 0; kt < 8; kt++) {
        f32x4_t S[8] = {};
#pragma unroll
        for (int pp = 0; pp < 8; pp++) {               // COMPILE-TIME phases
            short* buf = smKV[pp & 1];                 // kt*8 even -> pp&1
            if ((pp & 1) == 0) {
                *(int4*)&buf[row0 * 64 + cA8] = e0;
                *(int4*)&buf[row0 * 64 + cB8] = e1;
                *(int4*)&buf[row1 * 64 + cA8] = e2;
                *(int4*)&buf[row1 * 64 + cB8] = e3;
            } else {
                *(int4*)&buf[row0 * 64 + cA8] = o0;
                *(int4*)&buf[row0 * 64 + cB8] = o1;
                *(int4*)&buf[row1 * 64 + cA8] = o2;
                *(int4*)&buf[row1 * 64 + cB8] = o3;
            }
            __syncthreads();
            // issue loads for phase pp+2 (into the set just drained to LDS).
            // phase->data map: ph 0..3 = K d-chunk ph of kt; ph 4..7 = V chunk
            // q=ph-4 (h=q>>1 d-half, kh=q&1 kv-half) of kt.
            if (pp == 0) {
                LOADSET(e0, e1, e2, e3, Kb + (size_t)(kt * 128) * 256 + 128 + colb, 256);
            } else if (pp == 1) {
                LOADSET(o0, o1, o2, o3, Kb + (size_t)(kt * 128) * 256 + 192 + colb, 256);
            } else if (pp == 2) {
                LOADSET(e0, e1, e2, e3, Vb + (size_t)kt * 128 + colb, 1024);
            } else if (pp == 3) {
                LOADSET(o0, o1, o2, o3, Vb + (size_t)kt * 128 + 64 + colb, 1024);
            } else if (pp == 4) {
                LOADSET(e0, e1, e2, e3, Vb + (size_t)128 * 1024 + kt * 128 + colb, 1024);
            } else if (pp == 5) {
                LOADSET(o0, o1, o2, o3, Vb + (size_t)128 * 1024 + kt * 128 + 64 + colb, 1024);
            } else if (pp == 6) {
                if (kt < 7) LOADSET(e0, e1, e2, e3, Kb + (size_t)((kt + 1) * 128) * 256 + colb, 256);
            } else {
                if (kt < 7) LOADSET(o0, o1, o2, o3, Kb + (size_t)((kt + 1) * 128) * 256 + 64 + colb, 256);
            }
            if (pp < 4) {
                // ---- S += Q_dc K_dc^T (64-wide d-chunk dc = pp), 16x16 ----
                __builtin_amdgcn_s_setprio(1);
#pragma unroll
                for (int c2 = 0; c2 < 2; c2++)
#pragma unroll
                    for (int f = 0; f < 8; f++) {
                        bf16x8_t kb = *(const bf16x8_t*)
                            &buf[(f * 16 + fr) * 64 + (((c2 * 4 + qd) ^ (fr & 7)) << 3)];
                        S[f] = __builtin_amdgcn_mfma_f32_16x16x32_bf16(qa[pp * 2 + c2], kb, S[f], 0, 0, 0);
                    }
                __builtin_amdgcn_s_setprio(0);
                if (pp == 3) {
                    // ---- online softmax, shuffle-free common path ----
                    float pmax[4], tsum[4];
#pragma unroll
                    for (int r = 0; r < 4; r++) {
                        float mx = S[0][r];
#pragma unroll
                        for (int f = 1; f < 8; f++) mx = fmaxf(mx, S[f][r]);
                        pmax[r] = mx;
                        tsum[r] = 0.0f;
                    }
                    bool okl = (pmax[0] - mrun[0] <= 8.0f) & (pmax[1] - mrun[1] <= 8.0f)
                             & (pmax[2] - mrun[2] <= 8.0f) & (pmax[3] - mrun[3] <= 8.0f);
                    const bool trig = !__all(okl);
                    float alpha[4] = {1.0f, 1.0f, 1.0f, 1.0f};
                    if (trig) {
#pragma unroll
                        for (int r = 0; r < 4; r++) {
                            float mx = pmax[r];
#pragma unroll
                            for (int o = 1; o < 16; o <<= 1) mx = fmaxf(mx, __shfl_xor(mx, o));
                            const float mnew = fmaxf(mrun[r], mx);
                            alpha[r] = __expf(mrun[r] - mnew);
                            mrun[r] = mnew;
                            lrun[r] *= alpha[r];
                        }
                    }
                    if (fr == 0) {
#pragma unroll
                        for (int r = 0; r < 4; r++) alS[w * 16 + qd * 4 + r] = alpha[r];
                    }
                    if (lane == 0) flS[w] = trig ? 1 : 0;
#pragma unroll
                    for (int f = 0; f < 8; f++) {
#pragma unroll
                        for (int r = 0; r < 4; r++) {
                            const float pv = __expf(S[f][r] - mrun[r]);
                            tsum[r] += pv;
                            Pg[((w & 1) * 16 + qd * 4 + r) * PG_S + f * 16 + fr] = (short)f2bf_bits(pv);
                        }
                    }
#pragma unroll
                    for (int r = 0; r < 4; r++) lrun[r] += tsum[r];
                }
            } else {
                // ---- O += P @ V, 32x32x16 (d-half h, kv-half kh) ----
                const int q4 = pp - 4, h = q4 >> 1, kh = q4 & 1;  // compile-time
                if (pp == 4) {
                    // cross-wave defer-max rescale (this kt's alphas)
                    if (flS[2 * qg] | flS[2 * qg + 1]) {
#pragma unroll
                        for (int r = 0; r < 16; r++) {
                            const int qrw = (r & 3) + 8 * (r >> 2) + 4 * hi;
                            const float a = alS[qg * 32 + qrw];
#pragma unroll
                            for (int i = 0; i < 4; i++) Op4[i][r] *= a;
                        }
                    }
                }
                __builtin_amdgcn_s_setprio(1);
#pragma unroll
                for (int kf = 0; kf < 4; kf++) {
                    const bf16x8_t pa = *(const bf16x8_t*)&Pg[l31 * PG_S + kh * 64 + kf * 16 + hi * 8];
#pragma unroll
                    for (int dt = 0; dt < 2; dt++) {
                        const bf16x8_t vb = *(const bf16x8_t*)
                            &buf[(dh * 64 + dt * 32 + l31) * 64 + (((kf * 2 + hi) ^ (l31 & 7)) << 3)];
                        Op4[h * 2 + dt] =
                            __builtin_amdgcn_mfma_f32_32x32x16_bf16(pa, vb, Op4[h * 2 + dt], 0, 0, 0);
                    }
                }
                __builtin_amdgcn_s_setprio(0);
            }
        }
    }
#undef LOADSET

    // ---- finalize: reduce per-lane lrun, share via LDS, store bf16 Msg ----
#pragma unroll
    for (int r = 0; r < 4; r++) {
#pragma unroll
        for (int o = 1; o < 16; o <<= 1) lrun[r] += __shfl_xor(lrun[r], o);
    }
    if (fr == 0) {
#pragma unroll
        for (int r = 0; r < 4; r++) lrS[w * 16 + qd * 4 + r] = lrun[r];
    }
    __syncthreads();
    float inv16[16];
#pragma unroll
    for (int r = 0; r < 16; r++) {
        const int qrw = (r & 3) + 8 * (r >> 2) + 4 * hi;
        inv16[r] = 1.0f / lrS[qg * 32 + qrw];
    }
    unsigned short* outB = (unsigned short*)Msg + ((size_t)p * 3 + m) * BND_
                         + (size_t)batch * N_ * D_ + (size_t)(qt * 64 + qg * 32) * D_;
#pragma unroll
    for (int i = 0; i < 4; i++) {
        const int dcol = (i >> 1) * 128 + dh * 64 + (i & 1) * 32 + l31;
#pragma unroll
        for (int r = 0; r < 16; r++) {
            const int qrw = (r & 3) + 8 * (r >> 2) + 4 * hi;
            outB[(size_t)qrw * D_ + dcol] = f2bf_bits(Op4[i][r] * inv16[r]);
        }
    }
}

// ---------------------------------------------------------------------------
// Weight convert+transpose, all 5 weights in one dispatch (z selects).
// ---------------------------------------------------------------------------
__global__ __launch_bounds__(256) void wt_transpose_kernel(
    const float* __restrict__ W0, const float* __restrict__ W1,
    const float* __restrict__ W2, const float* __restrict__ W3,
    const float* __restrict__ W4, __hip_bfloat16* __restrict__ out)
{
    const int z = blockIdx.z;
    const float* in = z == 0 ? W0 : z == 1 ? W1 : z == 2 ? W2 : z == 3 ? W3 : W4;
    __hip_bfloat16* o = out + (size_t)z * D_ * D_;
    __shared__ float t[32][33];
    const int r0 = blockIdx.x * 32, c0 = blockIdx.y * 32;
    const int tx = threadIdx.x & 31, ty = threadIdx.x >> 5;
#pragma unroll
    for (int k = 0; k < 4; k++) {
        int r = ty + k * 8;
        t[r][tx] = in[(size_t)(r0 + r) * D_ + (c0 + tx)];
    }
    __syncthreads();
#pragma unroll
    for (int k = 0; k < 4; k++) {
        int r = ty + k * 8;
        o[(size_t)(c0 + r) * D_ + (r0 + tx)] = __float2bfloat16(t[tx][r]);
    }
}

// all 3 modality inputs fp32 -> bf16, one dispatch
__global__ void cvt3_kernel(const float* __restrict__ x0, const float* __restrict__ x1,
                            const float* __restrict__ x2, __hip_bfloat16* __restrict__ dst)
{
    const int z = blockIdx.z;
    const float* s = z == 0 ? x0 : z == 1 ? x1 : x2;
    const long long i = (long long)blockIdx.x * 256 + threadIdx.x;
    dst[(size_t)z * BND_ + i] = __float2bfloat16(s[i]);
}

// ---------------------------------------------------------------------------
// Fused hypergraph prep: per-modality block does count -> scan(N) -> scan(M)
// -> fill, all counters/offsets in LDS. Replaces zero/count/scan/scan/fill
// (5 serial launches -> 1).
// ---------------------------------------------------------------------------
__global__ __launch_bounds__(1024) void hg_prep_kernel(
    const int* __restrict__ i0, const int* __restrict__ i1, const int* __restrict__ i2,
    int* __restrict__ NOffs, int* __restrict__ EOffs,
    float* __restrict__ Dinv, float* __restrict__ Bnorm,
    int* __restrict__ NOrd, int* __restrict__ EOrd)
{
    const int z = blockIdx.z;
    const int* nidx = z == 0 ? i0 : z == 1 ? i1 : i2;
    const int* eidx = nidx + C_;
    NOffs += z * (N_ + 1); EOffs += z * (M_ + 1);
    Dinv += z * N_; Bnorm += z * M_;
    NOrd += z * C_; EOrd += z * C_;

    __shared__ int ncnt[N_];
    __shared__ int ecnt[M_];
    __shared__ int tmp[N_];
    __shared__ int noff[N_ + 1];
    __shared__ int eoff[M_ + 1];

    const int t = threadIdx.x;
    ncnt[t] = 0;
    if (t < M_) ecnt[t] = 0;
    __syncthreads();
#pragma unroll
    for (int c = t; c < C_; c += 1024) {
        atomicAdd(&ncnt[nidx[c]], 1);
        atomicAdd(&ecnt[eidx[c]], 1);
    }
    __syncthreads();
    // scan N (Hillis-Steele, inclusive)
    const int vn = ncnt[t];
    tmp[t] = vn;
    __syncthreads();
    for (int o = 1; o < N_; o <<= 1) {
        int x = (t >= o) ? tmp[t - o] : 0;
        __syncthreads();
        tmp[t] += x;
        __syncthreads();
    }
    noff[t] = tmp[t] - vn;
    NOffs[t] = tmp[t] - vn;
    if (t == N_ - 1) { noff[N_] = tmp[t]; NOffs[N_] = tmp[t]; }
    Dinv[t] = (vn > 0) ? (1.0f / (float)vn) : 0.0f;
    __syncthreads();
    // scan M
    int ve = 0;
    if (t < M_) { ve = ecnt[t]; tmp[t] = ve; }
    __syncthreads();
    for (int o = 1; o < M_; o <<= 1) {
        int x = (t >= o && t < M_) ? tmp[t - o] : 0;
        __syncthreads();
        if (t < M_) tmp[t] += x;
        __syncthreads();
    }
    if (t < M_) {
        eoff[t] = tmp[t] - ve;
        EOffs[t] = tmp[t] - ve;
        Bnorm[t] = (ve > 0) ? (1.0f / (float)ve) : 0.0f;
        if (t == M_ - 1) { eoff[M_] = tmp[t]; EOffs[M_] = tmp[t]; }
    }
    // reset counters, fill ordered lists
    ncnt[t] = 0;
    if (t < M_) ecnt[t] = 0;
    __syncthreads();
#pragma unroll
    for (int c = t; c < C_; c += 1024) {
        const int nd = nidx[c], ed = eidx[c];
        const int p1 = atomicAdd(&ncnt[nd], 1);
        NOrd[noff[nd] + p1] = c;
        const int p2 = atomicAdd(&ecnt[ed], 1);
        EOrd[eoff[ed] + p2] = c;
    }
}

// s1/s2 from bf16 xp; one wave per (md,b,n)
__global__ __launch_bounds__(64) void hg_s12_kernel(
    const unsigned short* __restrict__ Xp, const float* __restrict__ att,
    float* __restrict__ s1, float* __restrict__ s2)
{
    const int z = blockIdx.z;
    const int bid = blockIdx.x;
    const int b = bid >> 10;
    const int n = bid & (N_ - 1);
    const int lane = threadIdx.x;
    const unsigned short* xr = Xp + (size_t)z * BND_ + (size_t)(b * N_ + n) * D_;
    const ushort4 u = ((const ushort4*)xr)[lane];
    const float4 a1 = ((const float4*)att)[lane];
    const float4 a2 = ((const float4*)(att + D_))[lane];
    float d1 = bf2f(u.x) * a1.x + bf2f(u.y) * a1.y + bf2f(u.z) * a1.z + bf2f(u.w) * a1.w;
    float d2 = bf2f(u.x) * a2.x + bf2f(u.y) * a2.y + bf2f(u.z) * a2.z + bf2f(u.w) * a2.w;
#pragma unroll
    for (int o = 32; o > 0; o >>= 1) { d1 += __shfl_down(d1, o); d2 += __shfl_down(d2, o); }
    if (lane == 0) { s1[z * NB_ + n * 16 + b] = d1; s2[z * NB_ + n * 16 + b] = d2; }
}

// edge_s2[m,b]: atomic-free, grid (M_,1,3), 16 pos x 16 b LDS reduce.
__global__ __launch_bounds__(256) void hg_edge_s2_kernel(
    const int* __restrict__ i0, const int* __restrict__ i1, const int* __restrict__ i2,
    const int* __restrict__ eoffs, const int* __restrict__ eord,
    const float* __restrict__ s2, float* __restrict__ edge_s2)
{
    const int z = blockIdx.z;
    const int* nidx = z == 0 ? i0 : z == 1 ? i1 : i2;
    eoffs += z * (M_ + 1); eord += z * C_;
    s2 += z * NB_; edge_s2 += (size_t)z * M_ * 16;

    const int m = blockIdx.x;
    const int pos = threadIdx.x >> 4;
    const int b = threadIdx.x & 15;
    const int base = eoffs[m];
    const int len = eoffs[m + 1] - base;
    float acc = 0.0f;
#pragma unroll 4
    for (int i = pos; i < len; i += 16) {
        int c = eord[base + i];
        acc += s2[nidx[c] * 16 + b];
    }
    __shared__ float red[16][16];
    red[pos][b] = acc;
    __syncthreads();
    for (int s = 8; s > 0; s >>= 1) {
        if (pos < s) red[pos][b] += red[pos + s][b];
        __syncthreads();
    }
    if (pos == 0) edge_s2[m * 16 + b] = red[0][b];
}

__global__ __launch_bounds__(256) void hg_node_softmax_kernel(
    const int* __restrict__ i0, const int* __restrict__ i1, const int* __restrict__ i2,
    const int* __restrict__ noffs, const int* __restrict__ nord,
    const float* __restrict__ s1, const float* __restrict__ edge_s2,
    float* __restrict__ ee, float* __restrict__ inv_sum)
{
    const int z = blockIdx.z;
    const int* eidx = (z == 0 ? i0 : z == 1 ? i1 : i2) + C_;
    noffs += z * (N_ + 1); nord += z * C_;
    s1 += z * NB_; edge_s2 += (size_t)z * M_ * 16;
    ee += (size_t)z * C_ * 16; inv_sum += z * NB_;

    const int n = blockIdx.x;
    const int base = noffs[n];
    const int len = noffs[n + 1] - base;
    if (len == 0) return;
    const int cp = threadIdx.x >> 4;
    const int b = threadIdx.x & 15;
    __shared__ float red[16][16];
    const float s1nb = s1[n * 16 + b];

    float mx = -1e30f;
    for (int i = cp; i < len; i += 16) {
        int c = nord[base + i];
        float e = s1nb + edge_s2[eidx[c] * 16 + b];
        e = e > 0.0f ? e : 0.2f * e;      // leaky_relu 0.2
        mx = fmaxf(mx, e);
    }
    red[cp][b] = mx;
    __syncthreads();
    for (int s = 8; s > 0; s >>= 1) {
        if (cp < s) red[cp][b] = fmaxf(red[cp][b], red[cp + s][b]);
        __syncthreads();
    }
    mx = red[0][b];
    __syncthreads();

    float sm = 0.0f;
    for (int i = cp; i < len; i += 16) {
        int c = nord[base + i];
        float e = s1nb + edge_s2[eidx[c] * 16 + b];
        e = e > 0.0f ? e : 0.2f * e;
        float ex = __expf(e - mx);
        ee[c * 16 + b] = ex;
        sm += ex;
    }
    red[cp][b] = sm;
    __syncthreads();
    for (int s = 8; s > 0; s >>= 1) {
        if (cp < s) red[cp][b] += red[cp + s][b];
        __syncthreads();
    }
    if (cp == 0) inv_sum[n * 16 + b] = 1.0f / (red[0][b] + 1e-16f);
}

// Pack sorted-order gather arrays (kills dependent chains in xedge/xnode).
__global__ __launch_bounds__(256) void hg_pack_kernel(
    const int* __restrict__ i0, const int* __restrict__ i1, const int* __restrict__ i2,
    const int* __restrict__ nord, const int* __restrict__ eord,
    const float* __restrict__ ee, const float* __restrict__ inv_sum,
    int* __restrict__ EmS, int* __restrict__ NnS,
    float* __restrict__ CoefN, float* __restrict__ CoefE)
{
    const int z = blockIdx.z;
    const int* nidx = z == 0 ? i0 : z == 1 ? i1 : i2;
    const int* eidx = nidx + C_;
    nord += z * C_; eord += z * C_;
    ee += (size_t)z * C_ * 16; inv_sum += z * NB_;
    EmS += z * C_; NnS += z * C_;
    CoefN += (size_t)z * C_ * 16; CoefE += (size_t)z * C_ * 16;

    const int gid = blockIdx.x * 256 + threadIdx.x;   // C*16
    const int i = gid >> 4, b = gid & 15;
    const int c1 = nord[i], c2 = eord[i];
    const int n1 = nidx[c1], n2 = nidx[c2];
    if (b == 0) { EmS[i] = eidx[c1]; NnS[i] = n2; }
    CoefN[i * 16 + b] = ee[c1 * 16 + b] * inv_sum[n1 * 16 + b];
    CoefE[i * 16 + b] = ee[c2 * 16 + b] * inv_sum[n2 * 16 + b];
}

// x_edge[m,b,:] via packed arrays.
__global__ __launch_bounds__(256) void hg_xedge_kernel(
    const int* __restrict__ eoffs, const int* __restrict__ NnS,
    const float* __restrict__ CoefE, const unsigned short* __restrict__ Xp,
    const float* __restrict__ Bnorm, float* __restrict__ x_edge)
{
    const int z = blockIdx.z;
    eoffs += z * (M_ + 1); NnS += z * C_;
    CoefE += (size_t)z * C_ * 16;
    const unsigned short* xp = Xp + (size_t)z * BND_;
    Bnorm += z * M_; x_edge += (size_t)z * M_ * B_ * D_;

    const int m = blockIdx.x >> 4;
    const int b = blockIdx.x & 15;
    const int d = threadIdx.x;
    const int base = eoffs[m];
    const int len = eoffs[m + 1] - base;
    float acc = 0.0f;
#pragma unroll 4
    for (int i = 0; i < len; i++) {
        const int nn = NnS[base + i];
        const float cf = CoefE[(size_t)(base + i) * 16 + b];
        acc += cf * bf2f(xp[(size_t)(b * N_ + nn) * D_ + d]);
    }
    x_edge[((size_t)(m * 16 + b)) * D_ + d] = Bnorm[m] * acc;
}

// h[b,n,:] via packed arrays.
__global__ __launch_bounds__(256) void hg_xnode_kernel(
    const int* __restrict__ noffs, const int* __restrict__ EmS,
    const float* __restrict__ CoefN, const float* __restrict__ x_edge,
    const float* __restrict__ Dinv, __hip_bfloat16* __restrict__ Hbf)
{
    const int z = blockIdx.z;
    noffs += z * (N_ + 1); EmS += z * C_;
    CoefN += (size_t)z * C_ * 16;
    x_edge += (size_t)z * M_ * B_ * D_; Dinv += z * N_;
    __hip_bfloat16* hbf = Hbf + (size_t)z * BND_;

    const int n = blockIdx.x >> 4;
    const int b = blockIdx.x & 15;
    const int d = threadIdx.x;
    const int base = noffs[n];
    const int len = noffs[n + 1] - base;
    float acc = 0.0f;
#pragma unroll 4
    for (int i = 0; i < len; i++) {
        const int em = EmS[base + i];
        const float cf = CoefN[(size_t)(base + i) * 16 + b];
        acc += cf * x_edge[((size_t)(em * 16 + b)) * D_ + d];
    }
    hbf[((size_t)(b * N_ + n)) * D_ + d] = __float2bfloat16(Dinv[n] * acc);
}

// ---------------------------------------------------------------------------
// Host
// ---------------------------------------------------------------------------
static inline void launch_gemm(hipStream_t s, dim3 grid,
                               const void* A0, const void* A1, int lda, long long sA,
                               const void* B0, const void* B1, int ldb, long long sB,
                               void* Cv, int ldc, long long sC, long long cOff, long long pieceCs,
                               int K, int kPiece, int zBatches,
                               float scale, const float* bias,
                               const void* a0, const void* a1, int epi)
{
    gemm_nt_kernel<<<grid, 256, 0, s>>>((const __hip_bfloat16*)A0, (const __hip_bfloat16*)A1,
                                        lda, sA,
                                        (const __hip_bfloat16*)B0, (const __hip_bfloat16*)B1,
                                        ldb, sB,
                                        Cv, ldc, sC, cOff, pieceCs, K, kPiece, zBatches,
                                        scale, bias, a0, a1, epi);
}

extern "C" void kernel_launch(void* const* d_in, const int* in_sizes, int n_in,
                              void* d_out, int out_size, void* d_ws, size_t ws_size,
                              hipStream_t stream)
{
    (void)in_sizes; (void)n_in; (void)out_size; (void)ws_size;

    const float* x0 = (const float*)d_in[0];
    const float* x1 = (const float*)d_in[1];
    const float* x2 = (const float*)d_in[2];
    const int* h0 = (const int*)d_in[3];
    const int* h1 = (const int*)d_in[4];
    const int* h2 = (const int*)d_in[5];
    const float* W_hg  = (const float*)d_in[6];
    const float* att_hg= (const float*)d_in[7];
    const float* WQ = (const float*)d_in[8];
    const float* bQ = (const float*)d_in[9];
    const float* WK = (const float*)d_in[10];
    const float* bK = (const float*)d_in[11];
    const float* WV = (const float*)d_in[12];
    const float* bV = (const float*)d_in[13];
    const float* WO = (const float*)d_in[14];
    const float* bO = (const float*)d_in[15];
    float* outp = (float*)d_out;

    char* ws = (char*)d_ws;
    size_t off = 0;
    auto take = [&](size_t bytes) { size_t r = off; off += (bytes + 255) & ~(size_t)255; return r; };

    const size_t oWt   = take((size_t)5 * D_ * D_ * 2);          // 0.63 MB
    const size_t oHbf  = take((size_t)3 * BND_ * 2);             // 24 MB
    const size_t oKall = take((size_t)3 * BND_ * 2);             // 24 MB
    const size_t oVt   = take((size_t)3 * BND_ * 2);             // 24 MB
    const size_t oQall = take((size_t)3 * BND_ * 2);             // 24 MB
    const size_t oBIG  = take((size_t)6 * BND_ * 4);             // 96 MB: Xc+Xp | Msg(2x bf16)
    const size_t oXe   = take((size_t)3 * M_ * B_ * D_ * 4);     // 6 MB
    const size_t oEE   = take((size_t)3 * C_ * 16 * 4);
    const size_t oCoefN= take((size_t)3 * C_ * 16 * 4);
    const size_t oCoefE= take((size_t)3 * C_ * 16 * 4);
    const size_t oEmS  = take((size_t)3 * C_ * 4);
    const size_t oNnS  = take((size_t)3 * C_ * 4);
    const size_t oS1   = take((size_t)3 * NB_ * 4);
    const size_t oS2   = take((size_t)3 * NB_ * 4);
    const size_t oInv  = take((size_t)3 * NB_ * 4);
    const size_t oEs2  = take((size_t)3 * M_ * 16 * 4);
    const size_t oNOffs= take((size_t)3 * (N_ + 1) * 4);
    const size_t oEOffs= take((size_t)3 * (M_ + 1) * 4);
    const size_t oNOrd = take((size_t)3 * C_ * 4);
    const size_t oEOrd = take((size_t)3 * C_ * 4);
    const size_t oDinv = take((size_t)3 * N_ * 4);
    const size_t oBnorm= take((size_t)3 * M_ * 4);

    __hip_bfloat16* Wt   = (__hip_bfloat16*)(ws + oWt);
    __hip_bfloat16* Hbf  = (__hip_bfloat16*)(ws + oHbf);
    __hip_bfloat16* Kall = (__hip_bfloat16*)(ws + oKall);
    __hip_bfloat16* Vt   = (__hip_bfloat16*)(ws + oVt);
    __hip_bfloat16* Qall = (__hip_bfloat16*)(ws + oQall);
    __hip_bfloat16* Xc   = (__hip_bfloat16*)(ws + oBIG);
    __hip_bfloat16* Xp   = (__hip_bfloat16*)(ws + oBIG + (size_t)3 * BND_ * 2);
    __hip_bfloat16* Msg  = (__hip_bfloat16*)(ws + oBIG);       // bf16: [2][3*BND_]
    float* Xe   = (float*)(ws + oXe);
    float* EE   = (float*)(ws + oEE);
    float* CoefN= (float*)(ws + oCoefN);
    float* CoefE= (float*)(ws + oCoefE);
    int*   EmS  = (int*)(ws + oEmS);
    int*   NnS  = (int*)(ws + oNnS);
    float* S1f  = (float*)(ws + oS1);
    float* S2f  = (float*)(ws + oS2);
    float* Inv  = (float*)(ws + oInv);
    float* Es2  = (float*)(ws + oEs2);
    int*   NOffs = (int*)(ws + oNOffs);
    int*   EOffs = (int*)(ws + oEOffs);
    int*   NOrd  = (int*)(ws + oNOrd);
    int*   EOrd  = (int*)(ws + oEOrd);
    float* Dinv  = (float*)(ws + oDinv);
    float* Bnorm = (float*)(ws + oBnorm);

    const int WN = D_ * D_;
    __hip_bfloat16* WtHG = Wt;
    __hip_bfloat16* WtO  = Wt + (size_t)4 * WN;

    // -------- Phase 0: weights (one dispatch) -------------------------------
    wt_transpose_kernel<<<dim3(8, 8, 5), 256, 0, stream>>>(W_hg, WQ, WK, WV, WO, Wt);

    // -------- Phase 1: hypergraph conv, all modalities batched --------------
    cvt3_kernel<<<dim3((unsigned)(BND_ / 256), 1, 3), 256, 0, stream>>>(x0, x1, x2, Xc);
    hg_prep_kernel<<<dim3(1, 1, 3), 1024, 0, stream>>>(h0, h1, h2, NOffs, EOffs,
                                                       Dinv, Bnorm, NOrd, EOrd);
    launch_gemm(stream, dim3(BN_ / 128, D_ / 128, 3),
                Xc, Xc, D_, BND_, WtHG, WtHG, D_, 0,
                Xp, D_, BND_, 0, 0, D_, D_, 3,
                1.0f, nullptr, nullptr, nullptr, 1);
    hg_s12_kernel<<<dim3(BN_, 1, 3), 64, 0, stream>>>((const unsigned short*)Xp, att_hg, S1f, S2f);
    hg_edge_s2_kernel<<<dim3(M_, 1, 3), 256, 0, stream>>>(h0, h1, h2, EOffs, EOrd, S2f, Es2);
    hg_node_softmax_kernel<<<dim3(N_, 1, 3), 256, 0, stream>>>(h0, h1, h2, NOffs, NOrd,
                                                               S1f, Es2, EE, Inv);
    hg_pack_kernel<<<dim3(C_ * 16 / 256, 1, 3), 256, 0, stream>>>(h0, h1, h2, NOrd, EOrd,
                                                                  EE, Inv, EmS, NnS, CoefN, CoefE);
    hg_xedge_kernel<<<dim3(M_ * B_, 1, 3), 256, 0, stream>>>(EOffs, NnS, CoefE,
                                                             (const unsigned short*)Xp, Bnorm, Xe);
    hg_xnode_kernel<<<dim3(N_ * B_, 1, 3), 256, 0, stream>>>(NOffs, EmS, CoefN, Xe, Dinv, Hbf);

    // -------- Phase 2: K, V, Q fused in one dispatch ------------------------
    qkv_gemm_kernel<<<dim3(3 * BN_ / 128, D_ / 128, 3), 256, 0, stream>>>(
        Hbf, Wt, bQ, bK, bV, Qall, Kall, Vt);

    // -------- Phase 3: fused flash attention + output -----------------------
    flash_attn_kernel<<<dim3(1536, 1, 1), 256, 0, stream>>>(Qall, Kall, Vt, Msg);
    launch_gemm(stream, dim3(BN_ / 128, D_ / 128, 3),
                Hbf, Hbf, D_, BND_, WtO, WtO, D_, 0,
                outp, D_, BND_, 0, 0, D_, D_, 3,
                1.0f, bO,
                (const void*)Msg,
                (const void*)((const unsigned short*)Msg + (size_t)3 * BND_), 2);
}